// Round 11
// baseline (181.235 us; speedup 1.0000x reference)
//
#include <hip/hip_runtime.h>
#include <hip/hip_bf16.h>

// Problem constants (B=4, C=256, H=W=64, groups=8, heads=4)
#define BB   4
#define CC   256
#define NN   4096      // H*W
#define NH   4
#define HD   64
#define NG   8
#define GSZ  32        // channels per group
#define EPSV 1e-5f
#define SCALE_L2E 0.18033688f   // 64^-0.5 * log2(e), folded into q so softmax uses raw exp2

typedef __bf16 bf16x8 __attribute__((ext_vector_type(8)));
typedef float  f32x4  __attribute__((ext_vector_type(4)));

#define MFMA16(a, b, c)  __builtin_amdgcn_mfma_f32_16x16x32_bf16((a), (b), (c), 0, 0, 0)

#if __has_builtin(__builtin_amdgcn_exp2f)
#define EXP2F __builtin_amdgcn_exp2f
#else
#define EXP2F exp2f
#endif

// phase-edge fences for the counted-vmcnt pipeline (T3/T4)
#define WAITV(n)  asm volatile("s_waitcnt vmcnt(" #n ")" ::: "memory")
#define WAITL0    asm volatile("s_waitcnt lgkmcnt(0)" ::: "memory")
#define SBAR      __builtin_amdgcn_s_barrier()
#define SCHED0    __builtin_amdgcn_sched_barrier(0)

__device__ inline unsigned short f2bf(float f) {
    unsigned int u = __float_as_uint(f);
    u += 0x7fffu + ((u >> 16) & 1u);   // RNE
    return (unsigned short)(u >> 16);
}

// pack 8 fp32 -> 8 bf16 (truncate: uniform relative bias cancels in O/li) for PV A-operand
__device__ __forceinline__ bf16x8 pk8(const f32x4& p0, const f32x4& p1) {
    alignas(16) unsigned int u[4];
    u[0] = __builtin_amdgcn_perm(__float_as_uint(p0[1]), __float_as_uint(p0[0]), 0x07060302u);
    u[1] = __builtin_amdgcn_perm(__float_as_uint(p0[3]), __float_as_uint(p0[2]), 0x07060302u);
    u[2] = __builtin_amdgcn_perm(__float_as_uint(p1[1]), __float_as_uint(p1[0]), 0x07060302u);
    u[3] = __builtin_amdgcn_perm(__float_as_uint(p1[3]), __float_as_uint(p1[2]), 0x07060302u);
    return *reinterpret_cast<bf16x8*>(u);
}

// async global->LDS, 16B per lane; LDS dest is wave-uniform base + lane*16
__device__ __forceinline__ void async_ld16(void* lds, const void* g) {
    __builtin_amdgcn_global_load_lds(
        (const __attribute__((address_space(1))) unsigned int*)g,
        (__attribute__((address_space(3))) unsigned int*)lds, 16, 0, 0);
}

// ---------------- kernel 1: gn stats partials (blocks 0..255) + proj weight cvt (256..511) ----------------
// Each (b,g,s) block writes its partial sum to a disjoint slot -> no memset, no atomics.
__global__ void k_prep(const float* __restrict__ x, float* __restrict__ stats,
                       const float* __restrict__ wp, unsigned short* __restrict__ op) {
    int blk = blockIdx.x;
    int t = threadIdx.x;
    if (blk >= 256) {   // proj weight conversion
        int i = (blk - 256) * 256 + t;
        if (i < CC * CC) op[i] = f2bf(wp[i]);
        return;
    }
    int b = blk >> 6, g = (blk >> 3) & 7, s = blk & 7;
    const float* p = x + ((size_t)(b * CC + g * GSZ)) * NN + s * 16384;
    float s0 = 0.f, s1 = 0.f;
    #pragma unroll
    for (int i = 0; i < 64; ++i) { float v = p[i * 256 + t]; s0 += v; s1 += v * v; }
    #pragma unroll
    for (int m = 1; m <= 32; m <<= 1) { s0 += __shfl_xor(s0, m); s1 += __shfl_xor(s1, m); }
    __shared__ float ls[8];
    int w = t >> 6;
    if ((t & 63) == 0) { ls[w * 2] = s0; ls[w * 2 + 1] = s1; }
    __syncthreads();
    if (t == 0) {
        float a0 = ls[0] + ls[2] + ls[4] + ls[6];
        float a1 = ls[1] + ls[3] + ls[5] + ls[7];
        stats[((b * NG + g) * 8 + s) * 2 + 0] = a0;
        stats[((b * NG + g) * 8 + s) * 2 + 1] = a1;
    }
}

// ------- kernel 2: fold GN affine into per-batch qkv weights + bias -------
// grid 768 (one block per output row o); weight row read ONCE, looped over 4 batches.
// W'[b][o][c] = W[o][c] * gw[c]*inv(b,g);  bias'[b][o] = qb[o] + sum_c W[o][c]*(gb[c]-mean*Ac)
__global__ void __launch_bounds__(256)
k_tab(const float* __restrict__ wq, const float* __restrict__ gw, const float* __restrict__ gb,
      const float* __restrict__ qb, const float* __restrict__ stats,
      unsigned short* __restrict__ wqp, float* __restrict__ biasq) {
    int o = blockIdx.x, c = threadIdx.x;
    int g = c >> 5;
    float w = wq[o * CC + c];
    float gwc = gw[c], gbc = gb[c];
    __shared__ float ls[4][4];
    #pragma unroll
    for (int b = 0; b < 4; ++b) {
        float s0 = 0.f, s1 = 0.f;
        #pragma unroll
        for (int s = 0; s < 8; ++s) {
            s0 += stats[((b * NG + g) * 8 + s) * 2 + 0];
            s1 += stats[((b * NG + g) * 8 + s) * 2 + 1];
        }
        float mean = s0 * (1.0f / 131072.0f);
        float var  = s1 * (1.0f / 131072.0f) - mean * mean;
        float inv  = rsqrtf(var + EPSV);
        float Ac = gwc * inv;
        float Bc = gbc - mean * Ac;
        wqp[((size_t)b * 768 + o) * CC + c] = f2bf(w * Ac);
        float p = w * Bc;
        #pragma unroll
        for (int m = 1; m <= 32; m <<= 1) p += __shfl_xor(p, m);
        if ((c & 63) == 0) ls[b][c >> 6] = p;
    }
    __syncthreads();
    if (c < 4) biasq[c * 768 + o] = qb[o] + ls[c][0] + ls[c][1] + ls[c][2] + ls[c][3];
}

// ---------------- kernel 3: QKV GEMM directly on x (fp32), GN pre-folded into W' ----------------
__global__ void __launch_bounds__(256)
k_qkv(const float* __restrict__ x, const unsigned short* __restrict__ wqp,
      const float* __restrict__ biasq,
      unsigned short* __restrict__ qt, unsigned short* __restrict__ kt,
      unsigned short* __restrict__ vt) {
    int bx = blockIdx.x, by = blockIdx.y;
    int t = threadIdx.x, wave = t >> 6, lane = t & 63;
    int l15 = lane & 15, quad = lane >> 4;
    int wm = wave >> 1, wn = wave & 1;

    // A: 2 x 8192 @ [0, 16384); B(fp32): 2 x 16384 @ [16384, 49152). V epilogue reuses all.
    __shared__ alignas(16) unsigned char smem[49152];

    int nn0 = bx * 128;
    int b = nn0 >> 12, nbase = nn0 & 4095;

    const char* Ag = (const char*)wqp + (size_t)b * 393216 + (size_t)by * 65536;
    int row0 = t >> 2, slot = t & 3;
    size_t a0 = (size_t)row0 * 512 + slot * 16;
    size_t a1 = a0 + 64 * 512;
    unsigned int dstA = wave * 1024;                    // + lane*16 by HW

    // B staging: per-lane source with row rotation.
    int colsrc = (((lane & 31) * 16) - 32 * wave) & 511;
    const char* xrow = (const char*)x +
        (((size_t)(b * CC) + (wave * 8 + (lane >> 5))) * NN + nbase) * 4 + colsrc;

    auto stage = [&](int buf, int kk) {
        async_ld16(smem + buf * 8192 + dstA,        Ag + a0 + (size_t)kk * 64);
        async_ld16(smem + buf * 8192 + 4096 + dstA, Ag + a1 + (size_t)kk * 64);
        const char* bs = xrow + (size_t)kk * 32 * NN * 4;
        unsigned char* bd = smem + 16384 + buf * 16384 + wave * 4096;
        async_ld16(bd,        bs);
        async_ld16(bd + 1024, bs + (size_t)2 * NN * 4);
        async_ld16(bd + 2048, bs + (size_t)4 * NN * 4);
        async_ld16(bd + 3072, bs + (size_t)6 * NN * 4);
    };

    // per-lane rotated column offsets for the 4 B-fragments (f = 0..3)
    int colr[4];
    #pragma unroll
    for (int f = 0; f < 4; ++f)
        colr[f] = (((wn * 64 + f * 16 + l15) * 4) + quad * 32) & 511;

    f32x4 acc[4][4];
    #pragma unroll
    for (int i = 0; i < 4; ++i)
        #pragma unroll
        for (int j = 0; j < 4; ++j) acc[i][j] = (f32x4){0.f, 0.f, 0.f, 0.f};

    stage(0, 0);
    stage(1, 1);

    for (int kk = 0; kk < 8; ++kk) {
        if (kk < 7) { WAITV(6); } else { WAITV(0); }
        SCHED0;
        SBAR;
        SCHED0;
        int cur = kk & 1;
        bf16x8 af[4], bf[4];
        #pragma unroll
        for (int f = 0; f < 4; ++f)
            af[f] = *reinterpret_cast<const bf16x8*>(smem + cur * 8192 + (wm * 64 + f * 16 + l15) * 64 + quad * 16);
        #pragma unroll
        for (int f = 0; f < 4; ++f) {
            const unsigned char* fb = smem + 16384 + cur * 16384 + quad * 4096 + colr[f];
            alignas(16) unsigned int u[4];
            #pragma unroll
            for (int jj = 0; jj < 4; ++jj) {
                float xl = *reinterpret_cast<const float*>(fb + (2 * jj) * 512);
                float xh = *reinterpret_cast<const float*>(fb + (2 * jj + 1) * 512);
                asm("v_cvt_pk_bf16_f32 %0, %1, %2" : "=v"(u[jj]) : "v"(xl), "v"(xh));
            }
            bf[f] = *reinterpret_cast<const bf16x8*>(u);
        }
        #pragma unroll
        for (int fm = 0; fm < 4; ++fm)
            #pragma unroll
            for (int fn = 0; fn < 4; ++fn)
                acc[fm][fn] = MFMA16(af[fm], bf[fn], acc[fm][fn]);
        WAITL0;
        SCHED0;
        SBAR;
        SCHED0;
        if (kk < 6) stage(cur, kk + 2);
    }

    int s = by >> 1;
    if (s < 2) {
        #pragma unroll
        for (int fm = 0; fm < 4; ++fm) {
            int o = by * 128 + wm * 64 + fm * 16 + quad * 4;
            int h = (o >> 6) & 3, d0 = o & 63;
            float bias[4];
            #pragma unroll
            for (int r = 0; r < 4; ++r) bias[r] = biasq[b * 768 + o + r];
            #pragma unroll
            for (int fn = 0; fn < 4; ++fn) {
                int n = nbase + wn * 64 + fn * 16 + l15;
                alignas(8) unsigned short o4[4];
                if (s == 0) {
                    #pragma unroll
                    for (int r = 0; r < 4; ++r) o4[r] = f2bf((acc[fm][fn][r] + bias[r]) * SCALE_L2E);
                    *reinterpret_cast<uint2*>(qt + (((size_t)(b * NH + h) * NN) + n) * HD + d0) =
                        *reinterpret_cast<const uint2*>(o4);
                } else {
                    #pragma unroll
                    for (int r = 0; r < 4; ++r) o4[r] = f2bf(acc[fm][fn][r] + bias[r]);
                    *reinterpret_cast<uint2*>(kt + (((size_t)(b * NH + h) * NN) + n) * HD + d0) =
                        *reinterpret_cast<const uint2*>(o4);
                }
            }
        }
    } else {
        // ---- V: repack 128(d) x 128(n) tile via LDS, coalesced uint4 stores ----
        unsigned short* vtile = (unsigned short*)smem;    // [128][132] bf16
        #pragma unroll
        for (int fm = 0; fm < 4; ++fm) {
            int o  = by * 128 + wm * 64 + fm * 16 + quad * 4;
            int ol = wm * 64 + fm * 16 + quad * 4;
            float bias[4];
            #pragma unroll
            for (int r = 0; r < 4; ++r) bias[r] = biasq[b * 768 + o + r];
            #pragma unroll
            for (int fn = 0; fn < 4; ++fn) {
                int nl = wn * 64 + fn * 16 + l15;
                #pragma unroll
                for (int r = 0; r < 4; ++r)
                    vtile[(ol + r) * 132 + nl] = f2bf(acc[fm][fn][r] + bias[r]);
            }
        }
        __syncthreads();
        // slot s -> key n inverse perm: n = (s2<<4)|(s4<<3)|(s3<<2)|(s&3)
        int hbase = (by - 4) * 2;
        #pragma unroll
        for (int pass = 0; pass < 8; ++pass) {
            int row  = pass * 16 + (t >> 4);          // 0..127 = local d-row
            int col0 = (t & 15) * 8;                  // slot base
            int nb = (col0 & ~31) | ((col0 & 16) >> 1) | ((col0 & 8) >> 1);
            const unsigned short* src = vtile + row * 132 + nb;
            uint2 lo = *reinterpret_cast<const uint2*>(src);
            uint2 hi = *reinterpret_cast<const uint2*>(src + 16);
            uint4 o4 = make_uint4(lo.x, lo.y, hi.x, hi.y);
            int h = hbase + (row >> 6), d = row & 63;
            *reinterpret_cast<uint4*>(vt + ((size_t)(b * NH + h) * HD + d) * NN + nbase + col0) = o4;
        }
    }
}

// ---------------- kernel 4: flash attention, no k-split, cross-tile software pipeline (T15) ----------------
// grid (32 q-tiles of 128, B*NH) = 512 blocks, 2/CU. R10 showed counted-vmcnt depth-3 is NULL
// here: the bound is the intra-wave serial chain QK-MFMA -> exp/pack VALU -> PV-MFMA with no
// pipe overlap at 2 waves/SIMD. Fix: pipeline ACROSS tiles within the wave — phase t issues
// QK(t) into one S-set while exp/pack/li/PV(t-1) runs from the other set (zero data dep ->
// MFMA and trans/VALU interleave in one wave's stream). Two named S-sets (sE/sO, parity-
// selected, rule #20), 4 LDS buffers: phase t reads kbuf[t&3] + vbuf[(t-1)&3], stages tile
// t+3 into (t+3)&3 = (t-1)&3 AFTER the second barrier (V(t-1) reads drained by WAITL0+SBAR).
// li-MFMA gives lane-local row-sums -> normalization in epilogue, no partials/combine.
__global__ void __launch_bounds__(256, 2)
k_attn(const unsigned short* __restrict__ qt, const unsigned short* __restrict__ kt,
       const unsigned short* __restrict__ vt, unsigned short* __restrict__ ao) {
    int bh = blockIdx.y;
    int t = threadIdx.x, wave = t >> 6, lane = t & 63;
    int l15 = lane & 15, quad = lane >> 4;
    int qbase = blockIdx.x * 128 + wave * 32;
    const unsigned short* qp = qt + (size_t)bh * NN * HD;
    const unsigned short* kp = kt + (size_t)bh * NN * HD;
    const unsigned short* vp = vt + (size_t)bh * HD * NN;

    __shared__ alignas(16) unsigned char kbuf[4][8192];   // [64 keys][128 B]
    __shared__ alignas(16) unsigned char vbuf[4][8192];   // [64 d][128 B] (keys slot-permuted)

    int lr8 = lane >> 3, lc8 = lane & 7;
    int swz = lc8 ^ lr8;
    const char* ksrc = (const char*)kp + (size_t)(wave * 16 + lr8) * 128 + swz * 16;
    const char* vsrc = (const char*)vp + (size_t)(wave * 16 + lr8) * 8192 + swz * 16;
    unsigned int dstw = wave * 2048;                // + lane*16 by HW

    auto stage = [&](int buf) {                     // stages next 64-key tile, advances
        async_ld16(kbuf[buf] + dstw,        ksrc);
        async_ld16(kbuf[buf] + dstw + 1024, ksrc + 1024);       // K rows +8
        ksrc += 8192;
        async_ld16(vbuf[buf] + dstw,        vsrc);
        async_ld16(vbuf[buf] + dstw + 1024, vsrc + 8 * 8192);   // d-rows +8
        vsrc += 128;
    };

    bf16x8 qaA0 = *reinterpret_cast<const bf16x8*>(qp + (size_t)(qbase + l15) * HD + quad * 8);
    bf16x8 qaA1 = *reinterpret_cast<const bf16x8*>(qp + (size_t)(qbase + l15) * HD + 32 + quad * 8);
    bf16x8 qaB0 = *reinterpret_cast<const bf16x8*>(qp + (size_t)(qbase + 16 + l15) * HD + quad * 8);
    bf16x8 qaB1 = *reinterpret_cast<const bf16x8*>(qp + (size_t)(qbase + 16 + l15) * HD + 32 + quad * 8);
    // drain Q loads once, then detach from the vmcnt scoreboard (in-loop counted waits only)
    WAITV(0);
    asm volatile("" : "+v"(qaA0), "+v"(qaA1), "+v"(qaB0), "+v"(qaB1));

    const f32x4 Z4 = (f32x4){0.f, 0.f, 0.f, 0.f};   // persistent zero C-operand
    bf16x8 vone;
    #pragma unroll
    for (int i = 0; i < 8; ++i) vone[i] = (__bf16)1.0f;

    f32x4 OA[4], OB[4];
    #pragma unroll
    for (int i = 0; i < 4; ++i) { OA[i] = Z4; OB[i] = Z4; }
    f32x4 liAA = Z4, liBB = Z4;     // row-sum accumulators: [r] = li for query quad*4+r (+16 for B)

    int sx = l15 & 7;

    struct S8 { f32x4 a0[2], a1[2], b0[2], b1[2]; };
    S8 sE, sO;                      // even-phase / odd-phase S sets (compile-time selected)

    // QK(t): 8 ds_read + 16 MFMA into S (seeded from Z4). No dep on SM_PV below.
    auto qk_issue = [&](const unsigned char* kb, S8& S) {
        __builtin_amdgcn_s_setprio(1);
        #pragma unroll
        for (int s = 0; s < 2; ++s) {
            int r0 = (s * 32 + l15) * 128;
            bf16x8 k00 = *reinterpret_cast<const bf16x8*>(kb + r0 + ((quad ^ sx) * 16));
            bf16x8 k01 = *reinterpret_cast<const bf16x8*>(kb + r0 + (((quad + 4) ^ sx) * 16));
            bf16x8 k10 = *reinterpret_cast<const bf16x8*>(kb + r0 + 2048 + ((quad ^ sx) * 16));
            bf16x8 k11 = *reinterpret_cast<const bf16x8*>(kb + r0 + 2048 + (((quad + 4) ^ sx) * 16));
            S.a0[s] = MFMA16(k00, qaA0, Z4);  S.a0[s] = MFMA16(k01, qaA1, S.a0[s]);
            S.a1[s] = MFMA16(k10, qaA0, Z4);  S.a1[s] = MFMA16(k11, qaA1, S.a1[s]);
            S.b0[s] = MFMA16(k00, qaB0, Z4);  S.b0[s] = MFMA16(k01, qaB1, S.b0[s]);
            S.b1[s] = MFMA16(k10, qaB0, Z4);  S.b1[s] = MFMA16(k11, qaB1, S.b1[s]);
        }
        __builtin_amdgcn_s_setprio(0);
    };

    // exp/pack/li/PV for the PREVIOUS tile's S (overlaps the QK MFMAs above).
    auto sm_pv = [&](S8& S, const unsigned char* vbb) {
        #pragma unroll
        for (int s = 0; s < 2; ++s) {
            f32x4 pA0, pA1, pB0, pB1;
            #pragma unroll
            for (int r = 0; r < 4; ++r) {
                pA0[r] = EXP2F(S.a0[s][r]);  pA1[r] = EXP2F(S.a1[s][r]);
                pB0[r] = EXP2F(S.b0[s][r]);  pB1[r] = EXP2F(S.b1[s][r]);
            }
            bf16x8 fA = pk8(pA0, pA1);   // A-frag: slots quad*8..+7 of this chunk
            bf16x8 fB = pk8(pB0, pB1);

            __builtin_amdgcn_s_setprio(1);
            liAA = MFMA16(fA, vone, liAA);   // D[q][*] = sum_k P[q][k], all cols equal
            liBB = MFMA16(fB, vone, liBB);

            #pragma unroll
            for (int dc = 0; dc < 4; ++dc) {
                const unsigned char* vrow = vbb + (dc * 16 + l15) * 128;
                bf16x8 vv = *reinterpret_cast<const bf16x8*>(vrow + (((s * 4 + quad) ^ sx) * 16));
                OA[dc] = MFMA16(fA, vv, OA[dc]);   // D: row=q=quad*4+r, col=d=l15
                OB[dc] = MFMA16(fB, vv, OB[dc]);
            }
            __builtin_amdgcn_s_setprio(0);
        }
    };

    // prologue: 3 tiles in flight (12 loads)
    stage(0);
    stage(1);
    stage(2);

    for (int p = 0; p < 16; ++p) {
        #pragma unroll
        for (int j = 0; j < 4; ++j) {       // phase t = 4p + j: QK(t), PV(t-1)
            if (p < 15) { WAITV(8); }
            else {
                if (j < 2)      { WAITV(8); }
                else if (j == 2){ WAITV(4); }
                else            { WAITV(0); }
            }
            SCHED0;
            SBAR;
            SCHED0;
            if (j & 1) {
                qk_issue(kbuf[j], sO);
                sm_pv(sE, vbuf[(j + 3) & 3]);
            } else {
                qk_issue(kbuf[j], sE);
                if (p > 0 || j > 0) sm_pv(sO, vbuf[(j + 3) & 3]);
            }
            WAITL0;
            SCHED0;
            SBAR;
            SCHED0;
            if (p < 15 || j == 0) stage((j + 3) & 3);   // stage tile t+3
        }
    }
    // epilogue: PV(63) (t=63 odd -> S in sO; tile 63 lives in vbuf[3], never overwritten)
    sm_pv(sO, vbuf[3]);

    // lane-local normalization: every lane holds li for its 4 queries (A and B chunks)
    f32x4 rA, rB;
    #pragma unroll
    for (int r = 0; r < 4; ++r) { rA[r] = 1.0f / liAA[r]; rB[r] = 1.0f / liBB[r]; }

    int b = bh >> 2, h = bh & 3;
    #pragma unroll
    for (int dc = 0; dc < 4; ++dc) {
        #pragma unroll
        for (int r = 0; r < 4; ++r) {
            int qA = qbase + quad * 4 + r;
            ao[((size_t)(b * NN) + qA) * CC + h * HD + dc * 16 + l15]      = f2bf(OA[dc][r] * rA[r]);
            ao[((size_t)(b * NN) + qA + 16) * CC + h * HD + dc * 16 + l15] = f2bf(OB[dc][r] * rB[r]);
        }
    }
}

// ---------------- kernel 5: proj GEMM 64x64 tile + bias + residual, counted-vmcnt ----------------
// B = normalized ao (bf16, token-major) -> plain global_load_lds stream like A.
__global__ void __launch_bounds__(256)
k_proj(const unsigned short* __restrict__ ao, const unsigned short* __restrict__ wp,
       const float* __restrict__ pb, const float* __restrict__ x,
       float* __restrict__ out) {
    int bx = blockIdx.x, by = blockIdx.y;
    int t = threadIdx.x, wave = t >> 6, lane = t & 63;
    int l15 = lane & 15, quad = lane >> 4;
    int wm = wave >> 1, wn = wave & 1;

    __shared__ alignas(16) unsigned char At[2][4096];   // [64 rows][32 c]
    __shared__ alignas(16) unsigned char Bt[2][4096];   // [64 tokens][32 c]

    const char* Ag = (const char*)wp + (size_t)by * 32768;
    const char* Bg = (const char*)ao + (size_t)bx * 32768;
    int row0 = t >> 2, slot = t & 3;
    size_t a0 = (size_t)row0 * 512 + slot * 16;
    unsigned int dst0 = wave * 1024;

    auto stage = [&](int buf, int kk) {
        size_t ko = (size_t)kk * 64;
        async_ld16(At[buf] + dst0, Ag + a0 + ko);
        async_ld16(Bt[buf] + dst0, Bg + a0 + ko);
    };

    f32x4 acc[2][2];
    #pragma unroll
    for (int i = 0; i < 2; ++i)
        #pragma unroll
        for (int j = 0; j < 2; ++j) acc[i][j] = (f32x4){0.f, 0.f, 0.f, 0.f};

    stage(0, 0);
    stage(1, 1);

    for (int kk = 0; kk < 8; ++kk) {
        if (kk < 7) { WAITV(2); } else { WAITV(0); }
        SCHED0;
        SBAR;
        SCHED0;
        int cur = kk & 1;
        bf16x8 af[2], bf[2];
        #pragma unroll
        for (int f = 0; f < 2; ++f) {
            af[f] = *reinterpret_cast<const bf16x8*>(At[cur] + (wm * 32 + f * 16 + l15) * 64 + quad * 16);
            bf[f] = *reinterpret_cast<const bf16x8*>(Bt[cur] + (wn * 32 + f * 16 + l15) * 64 + quad * 16);
        }
        #pragma unroll
        for (int fm = 0; fm < 2; ++fm)
            #pragma unroll
            for (int fn = 0; fn < 2; ++fn)
                acc[fm][fn] = MFMA16(af[fm], bf[fn], acc[fm][fn]);
        WAITL0;
        SCHED0;
        SBAR;
        SCHED0;
        if (kk < 6) stage(cur, kk + 2);
    }

    int nn0 = bx * 64;
    int b = nn0 >> 12, nbase = nn0 & 4095;
    #pragma unroll
    for (int fm = 0; fm < 2; ++fm) {
        int o = by * 64 + wm * 32 + fm * 16 + quad * 4;
        float bias[4];
        #pragma unroll
        for (int r = 0; r < 4; ++r) bias[r] = pb[o + r];
        #pragma unroll
        for (int fn = 0; fn < 2; ++fn) {
            int n = nbase + wn * 32 + fn * 16 + l15;
            #pragma unroll
            for (int r = 0; r < 4; ++r) {
                size_t idx = ((size_t)(b * CC + o + r)) * NN + n;
                out[idx] = acc[fm][fn][r] + bias[r] + x[idx];
            }
        }
    }
}

extern "C" void kernel_launch(void* const* d_in, const int* in_sizes, int n_in,
                              void* d_out, int out_size, void* d_ws, size_t ws_size,
                              hipStream_t stream) {
    const float* x     = (const float*)d_in[0];
    const float* gw    = (const float*)d_in[1];
    const float* gb    = (const float*)d_in[2];
    const float* qkvw  = (const float*)d_in[3];
    const float* qkvb  = (const float*)d_in[4];
    const float* projw = (const float*)d_in[5];
    const float* projb = (const float*)d_in[6];
    float* out = (float*)d_out;

    char* w = (char*)d_ws;
    size_t off = 0;
    unsigned short* qt = (unsigned short*)(w + off); off += (size_t)BB * NH * NN * HD * 2;  // 8 MB
    unsigned short* kt = (unsigned short*)(w + off); off += (size_t)BB * NH * NN * HD * 2;  // 8 MB
    unsigned short* vt = (unsigned short*)(w + off); off += (size_t)BB * NH * HD * NN * 2;  // 8 MB
    unsigned short* ao = (unsigned short*)(w + off); off += (size_t)BB * NN * CC * 2;       // 8 MB (normalized O)
    unsigned short* wqp = (unsigned short*)(w + off); off += (size_t)BB * 3 * CC * CC * 2;  // 1.5 MB (per-batch W')
    float* biasq = (float*)(w + off); off += (size_t)BB * 3 * CC * sizeof(float);           // 12 KB
    unsigned short* wpb = (unsigned short*)(w + off); off += (size_t)CC * CC * 2;           // 128 KB
    float* stats = (float*)(w + off); off += (size_t)BB * NG * 8 * 2 * sizeof(float);       // 4 KB (partials)

    k_prep<<<512, 256, 0, stream>>>(x, stats, projw, wpb);
    k_tab<<<768, 256, 0, stream>>>(qkvw, gw, gb, qkvb, stats, wqp, biasq);
    k_qkv<<<dim3(BB * NN / 128, 6), 256, 0, stream>>>(x, wqp, biasq, qt, kt, vt);
    k_attn<<<dim3(NN / 128, BB * NH), 256, 0, stream>>>(qt, kt, vt, ao);
    k_proj<<<dim3(BB * NN / 64, CC / 64), 256, 0, stream>>>(ao, wpb, projb, x, out);
}

// Round 12
// 180.756 us; speedup vs baseline: 1.0026x; 1.0026x over previous
//
#include <hip/hip_runtime.h>
#include <hip/hip_bf16.h>

// Problem constants (B=4, C=256, H=W=64, groups=8, heads=4)
#define BB   4
#define CC   256
#define NN   4096      // H*W
#define NH   4
#define HD   64
#define NG   8
#define GSZ  32        // channels per group
#define EPSV 1e-5f
#define SCALE_L2E 0.18033688f   // 64^-0.5 * log2(e), folded into q so softmax uses raw exp2

typedef __bf16 bf16x8 __attribute__((ext_vector_type(8)));
typedef float  f32x4  __attribute__((ext_vector_type(4)));

#define MFMA16(a, b, c)  __builtin_amdgcn_mfma_f32_16x16x32_bf16((a), (b), (c), 0, 0, 0)

#if __has_builtin(__builtin_amdgcn_exp2f)
#define EXP2F __builtin_amdgcn_exp2f
#else
#define EXP2F exp2f
#endif

// phase-edge fences for the counted-vmcnt pipeline (T3/T4)
#define WAITV(n)  asm volatile("s_waitcnt vmcnt(" #n ")" ::: "memory")
#define WAITL0    asm volatile("s_waitcnt lgkmcnt(0)" ::: "memory")
#define SBAR      __builtin_amdgcn_s_barrier()
#define SCHED0    __builtin_amdgcn_sched_barrier(0)

__device__ inline unsigned short f2bf(float f) {
    unsigned int u = __float_as_uint(f);
    u += 0x7fffu + ((u >> 16) & 1u);   // RNE
    return (unsigned short)(u >> 16);
}

// pack 8 fp32 -> 8 bf16 (truncate: uniform relative bias cancels in O/li) for PV A-operand
__device__ __forceinline__ bf16x8 pk8(const f32x4& p0, const f32x4& p1) {
    alignas(16) unsigned int u[4];
    u[0] = __builtin_amdgcn_perm(__float_as_uint(p0[1]), __float_as_uint(p0[0]), 0x07060302u);
    u[1] = __builtin_amdgcn_perm(__float_as_uint(p0[3]), __float_as_uint(p0[2]), 0x07060302u);
    u[2] = __builtin_amdgcn_perm(__float_as_uint(p1[1]), __float_as_uint(p1[0]), 0x07060302u);
    u[3] = __builtin_amdgcn_perm(__float_as_uint(p1[3]), __float_as_uint(p1[2]), 0x07060302u);
    return *reinterpret_cast<bf16x8*>(u);
}

// async global->LDS, 16B per lane; LDS dest is wave-uniform base + lane*16
__device__ __forceinline__ void async_ld16(void* lds, const void* g) {
    __builtin_amdgcn_global_load_lds(
        (const __attribute__((address_space(1))) unsigned int*)g,
        (__attribute__((address_space(3))) unsigned int*)lds, 16, 0, 0);
}

// ---------------- kernel 1: gn stats partials (blocks 0..255) + proj weight cvt (256..511) ----------------
// Each (b,g,s) block writes its partial sum to a disjoint slot -> no memset, no atomics.
__global__ void k_prep(const float* __restrict__ x, float* __restrict__ stats,
                       const float* __restrict__ wp, unsigned short* __restrict__ op) {
    int blk = blockIdx.x;
    int t = threadIdx.x;
    if (blk >= 256) {   // proj weight conversion
        int i = (blk - 256) * 256 + t;
        if (i < CC * CC) op[i] = f2bf(wp[i]);
        return;
    }
    int b = blk >> 6, g = (blk >> 3) & 7, s = blk & 7;
    const float* p = x + ((size_t)(b * CC + g * GSZ)) * NN + s * 16384;
    float s0 = 0.f, s1 = 0.f;
    #pragma unroll
    for (int i = 0; i < 64; ++i) { float v = p[i * 256 + t]; s0 += v; s1 += v * v; }
    #pragma unroll
    for (int m = 1; m <= 32; m <<= 1) { s0 += __shfl_xor(s0, m); s1 += __shfl_xor(s1, m); }
    __shared__ float ls[8];
    int w = t >> 6;
    if ((t & 63) == 0) { ls[w * 2] = s0; ls[w * 2 + 1] = s1; }
    __syncthreads();
    if (t == 0) {
        float a0 = ls[0] + ls[2] + ls[4] + ls[6];
        float a1 = ls[1] + ls[3] + ls[5] + ls[7];
        stats[((b * NG + g) * 8 + s) * 2 + 0] = a0;
        stats[((b * NG + g) * 8 + s) * 2 + 1] = a1;
    }
}

// ------- kernel 2: fold GN affine into per-batch qkv weights + bias -------
// grid 768 (one block per output row o); weight row read ONCE, looped over 4 batches.
// W'[b][o][c] = W[o][c] * gw[c]*inv(b,g);  bias'[b][o] = qb[o] + sum_c W[o][c]*(gb[c]-mean*Ac)
__global__ void __launch_bounds__(256)
k_tab(const float* __restrict__ wq, const float* __restrict__ gw, const float* __restrict__ gb,
      const float* __restrict__ qb, const float* __restrict__ stats,
      unsigned short* __restrict__ wqp, float* __restrict__ biasq) {
    int o = blockIdx.x, c = threadIdx.x;
    int g = c >> 5;
    float w = wq[o * CC + c];
    float gwc = gw[c], gbc = gb[c];
    __shared__ float ls[4][4];
    #pragma unroll
    for (int b = 0; b < 4; ++b) {
        float s0 = 0.f, s1 = 0.f;
        #pragma unroll
        for (int s = 0; s < 8; ++s) {
            s0 += stats[((b * NG + g) * 8 + s) * 2 + 0];
            s1 += stats[((b * NG + g) * 8 + s) * 2 + 1];
        }
        float mean = s0 * (1.0f / 131072.0f);
        float var  = s1 * (1.0f / 131072.0f) - mean * mean;
        float inv  = rsqrtf(var + EPSV);
        float Ac = gwc * inv;
        float Bc = gbc - mean * Ac;
        wqp[((size_t)b * 768 + o) * CC + c] = f2bf(w * Ac);
        float p = w * Bc;
        #pragma unroll
        for (int m = 1; m <= 32; m <<= 1) p += __shfl_xor(p, m);
        if ((c & 63) == 0) ls[b][c >> 6] = p;
    }
    __syncthreads();
    if (c < 4) biasq[c * 768 + o] = qb[o] + ls[c][0] + ls[c][1] + ls[c][2] + ls[c][3];
}

// ---------------- kernel 3: QKV GEMM directly on x (fp32), GN pre-folded into W' ----------------
__global__ void __launch_bounds__(256)
k_qkv(const float* __restrict__ x, const unsigned short* __restrict__ wqp,
      const float* __restrict__ biasq,
      unsigned short* __restrict__ qt, unsigned short* __restrict__ kt,
      unsigned short* __restrict__ vt) {
    int bx = blockIdx.x, by = blockIdx.y;
    int t = threadIdx.x, wave = t >> 6, lane = t & 63;
    int l15 = lane & 15, quad = lane >> 4;
    int wm = wave >> 1, wn = wave & 1;

    // A: 2 x 8192 @ [0, 16384); B(fp32): 2 x 16384 @ [16384, 49152). V epilogue reuses all.
    __shared__ alignas(16) unsigned char smem[49152];

    int nn0 = bx * 128;
    int b = nn0 >> 12, nbase = nn0 & 4095;

    const char* Ag = (const char*)wqp + (size_t)b * 393216 + (size_t)by * 65536;
    int row0 = t >> 2, slot = t & 3;
    size_t a0 = (size_t)row0 * 512 + slot * 16;
    size_t a1 = a0 + 64 * 512;
    unsigned int dstA = wave * 1024;                    // + lane*16 by HW

    // B staging: per-lane source with row rotation.
    int colsrc = (((lane & 31) * 16) - 32 * wave) & 511;
    const char* xrow = (const char*)x +
        (((size_t)(b * CC) + (wave * 8 + (lane >> 5))) * NN + nbase) * 4 + colsrc;

    auto stage = [&](int buf, int kk) {
        async_ld16(smem + buf * 8192 + dstA,        Ag + a0 + (size_t)kk * 64);
        async_ld16(smem + buf * 8192 + 4096 + dstA, Ag + a1 + (size_t)kk * 64);
        const char* bs = xrow + (size_t)kk * 32 * NN * 4;
        unsigned char* bd = smem + 16384 + buf * 16384 + wave * 4096;
        async_ld16(bd,        bs);
        async_ld16(bd + 1024, bs + (size_t)2 * NN * 4);
        async_ld16(bd + 2048, bs + (size_t)4 * NN * 4);
        async_ld16(bd + 3072, bs + (size_t)6 * NN * 4);
    };

    // per-lane rotated column offsets for the 4 B-fragments (f = 0..3)
    int colr[4];
    #pragma unroll
    for (int f = 0; f < 4; ++f)
        colr[f] = (((wn * 64 + f * 16 + l15) * 4) + quad * 32) & 511;

    f32x4 acc[4][4];
    #pragma unroll
    for (int i = 0; i < 4; ++i)
        #pragma unroll
        for (int j = 0; j < 4; ++j) acc[i][j] = (f32x4){0.f, 0.f, 0.f, 0.f};

    stage(0, 0);
    stage(1, 1);

    for (int kk = 0; kk < 8; ++kk) {
        if (kk < 7) { WAITV(6); } else { WAITV(0); }
        SCHED0;
        SBAR;
        SCHED0;
        int cur = kk & 1;
        bf16x8 af[4], bf[4];
        #pragma unroll
        for (int f = 0; f < 4; ++f)
            af[f] = *reinterpret_cast<const bf16x8*>(smem + cur * 8192 + (wm * 64 + f * 16 + l15) * 64 + quad * 16);
        #pragma unroll
        for (int f = 0; f < 4; ++f) {
            const unsigned char* fb = smem + 16384 + cur * 16384 + quad * 4096 + colr[f];
            alignas(16) unsigned int u[4];
            #pragma unroll
            for (int jj = 0; jj < 4; ++jj) {
                float xl = *reinterpret_cast<const float*>(fb + (2 * jj) * 512);
                float xh = *reinterpret_cast<const float*>(fb + (2 * jj + 1) * 512);
                asm("v_cvt_pk_bf16_f32 %0, %1, %2" : "=v"(u[jj]) : "v"(xl), "v"(xh));
            }
            bf[f] = *reinterpret_cast<const bf16x8*>(u);
        }
        #pragma unroll
        for (int fm = 0; fm < 4; ++fm)
            #pragma unroll
            for (int fn = 0; fn < 4; ++fn)
                acc[fm][fn] = MFMA16(af[fm], bf[fn], acc[fm][fn]);
        WAITL0;
        SCHED0;
        SBAR;
        SCHED0;
        if (kk < 6) stage(cur, kk + 2);
    }

    int s = by >> 1;
    if (s < 2) {
        #pragma unroll
        for (int fm = 0; fm < 4; ++fm) {
            int o = by * 128 + wm * 64 + fm * 16 + quad * 4;
            int h = (o >> 6) & 3, d0 = o & 63;
            float bias[4];
            #pragma unroll
            for (int r = 0; r < 4; ++r) bias[r] = biasq[b * 768 + o + r];
            #pragma unroll
            for (int fn = 0; fn < 4; ++fn) {
                int n = nbase + wn * 64 + fn * 16 + l15;
                alignas(8) unsigned short o4[4];
                if (s == 0) {
                    #pragma unroll
                    for (int r = 0; r < 4; ++r) o4[r] = f2bf((acc[fm][fn][r] + bias[r]) * SCALE_L2E);
                    *reinterpret_cast<uint2*>(qt + (((size_t)(b * NH + h) * NN) + n) * HD + d0) =
                        *reinterpret_cast<const uint2*>(o4);
                } else {
                    #pragma unroll
                    for (int r = 0; r < 4; ++r) o4[r] = f2bf(acc[fm][fn][r] + bias[r]);
                    *reinterpret_cast<uint2*>(kt + (((size_t)(b * NH + h) * NN) + n) * HD + d0) =
                        *reinterpret_cast<const uint2*>(o4);
                }
            }
        }
    } else {
        // ---- V: repack 128(d) x 128(n) tile via LDS, coalesced uint4 stores ----
        unsigned short* vtile = (unsigned short*)smem;    // [128][132] bf16
        #pragma unroll
        for (int fm = 0; fm < 4; ++fm) {
            int o  = by * 128 + wm * 64 + fm * 16 + quad * 4;
            int ol = wm * 64 + fm * 16 + quad * 4;
            float bias[4];
            #pragma unroll
            for (int r = 0; r < 4; ++r) bias[r] = biasq[b * 768 + o + r];
            #pragma unroll
            for (int fn = 0; fn < 4; ++fn) {
                int nl = wn * 64 + fn * 16 + l15;
                #pragma unroll
                for (int r = 0; r < 4; ++r)
                    vtile[(ol + r) * 132 + nl] = f2bf(acc[fm][fn][r] + bias[r]);
            }
        }
        __syncthreads();
        // slot s -> key n inverse perm: n = (s2<<4)|(s4<<3)|(s3<<2)|(s&3)
        int hbase = (by - 4) * 2;
        #pragma unroll
        for (int pass = 0; pass < 8; ++pass) {
            int row  = pass * 16 + (t >> 4);          // 0..127 = local d-row
            int col0 = (t & 15) * 8;                  // slot base
            int nb = (col0 & ~31) | ((col0 & 16) >> 1) | ((col0 & 8) >> 1);
            const unsigned short* src = vtile + row * 132 + nb;
            uint2 lo = *reinterpret_cast<const uint2*>(src);
            uint2 hi = *reinterpret_cast<const uint2*>(src + 16);
            uint4 o4 = make_uint4(lo.x, lo.y, hi.x, hi.y);
            int h = hbase + (row >> 6), d = row & 63;
            *reinterpret_cast<uint4*>(vt + ((size_t)(b * NH + h) * HD + d) * NN + nbase + col0) = o4;
        }
    }
}

// ---------------- kernel 4: flash attention, k-split 2 (4 blocks/CU restores MfmaUtil 48) ----------------
// grid (32 q-tiles of 128, B*NH, 2 key-splits); block 256 = 4 waves; wave owns 32 queries.
// The R7-bench body verbatim (measured 70.0 us). Scheduling levers at 2 blocks/CU all failed
// (R10 counted-vmcnt, R11 T15 pipeline) -> residency, not dependency, is the lever.
// li-MFMA row-sums -> lip; unnormalized partials to op0/op1; combine fused into k_proj.
__global__ void __launch_bounds__(256, 4)
k_attn(const unsigned short* __restrict__ qt, const unsigned short* __restrict__ kt,
       const unsigned short* __restrict__ vt,
       unsigned short* __restrict__ op0, unsigned short* __restrict__ op1,
       float* __restrict__ lip) {
    int bh = blockIdx.y;
    int split = blockIdx.z;
    int t = threadIdx.x, wave = t >> 6, lane = t & 63;
    int l15 = lane & 15, quad = lane >> 4;
    int qbase = blockIdx.x * 128 + wave * 32;
    int kbase = split * 2048;
    const unsigned short* qp = qt + (size_t)bh * NN * HD;
    const unsigned short* kp = kt + (size_t)bh * NN * HD;
    const unsigned short* vp = vt + (size_t)bh * HD * NN;

    __shared__ alignas(16) unsigned char kbuf[2][8192];   // [64 keys][128 B]
    __shared__ alignas(16) unsigned char vbuf[2][8192];   // [64 d][128 B] (keys slot-permuted)

    int lr8 = lane >> 3, lc8 = lane & 7;
    int swz = lc8 ^ lr8;
    const char* ksrc = (const char*)kp + (size_t)(kbase + wave * 16 + lr8) * 128 + swz * 16;
    const char* vsrc = (const char*)vp + (size_t)(wave * 16 + lr8) * 8192 + (size_t)kbase * 2 + swz * 16;
    unsigned int dstw = wave * 2048;                // + lane*16 by HW

    auto stage = [&](int buf) {                     // stages next 64-key tile, advances
        async_ld16(kbuf[buf] + dstw,        ksrc);
        async_ld16(kbuf[buf] + dstw + 1024, ksrc + 1024);       // K rows +8
        ksrc += 8192;
        async_ld16(vbuf[buf] + dstw,        vsrc);
        async_ld16(vbuf[buf] + dstw + 1024, vsrc + 8 * 8192);   // d-rows +8
        vsrc += 128;
    };

    bf16x8 qaA0 = *reinterpret_cast<const bf16x8*>(qp + (size_t)(qbase + l15) * HD + quad * 8);
    bf16x8 qaA1 = *reinterpret_cast<const bf16x8*>(qp + (size_t)(qbase + l15) * HD + 32 + quad * 8);
    bf16x8 qaB0 = *reinterpret_cast<const bf16x8*>(qp + (size_t)(qbase + 16 + l15) * HD + quad * 8);
    bf16x8 qaB1 = *reinterpret_cast<const bf16x8*>(qp + (size_t)(qbase + 16 + l15) * HD + 32 + quad * 8);

    const f32x4 Z4 = (f32x4){0.f, 0.f, 0.f, 0.f};   // persistent zero C-operand
    bf16x8 vone;
    #pragma unroll
    for (int i = 0; i < 8; ++i) vone[i] = (__bf16)1.0f;

    f32x4 OA[4], OB[4];
    #pragma unroll
    for (int i = 0; i < 4; ++i) { OA[i] = Z4; OB[i] = Z4; }
    f32x4 liAA = Z4, liBB = Z4;     // row-sum accumulators: [r] = li for query quad*4+r (+16 for B)

    int sx = l15 & 7;

    auto compute = [&](const unsigned char* kb, const unsigned char* vbb) {
        f32x4 sA0[2], sA1[2], sB0[2], sB1[2];
        // --- QK burst: both chunks, 16 independent MFMAs, C seeded from Z4 ---
        __builtin_amdgcn_s_setprio(1);
        #pragma unroll
        for (int s = 0; s < 2; ++s) {
            int r0 = (s * 32 + l15) * 128;
            bf16x8 k00 = *reinterpret_cast<const bf16x8*>(kb + r0 + ((quad ^ sx) * 16));
            bf16x8 k01 = *reinterpret_cast<const bf16x8*>(kb + r0 + (((quad + 4) ^ sx) * 16));
            bf16x8 k10 = *reinterpret_cast<const bf16x8*>(kb + r0 + 2048 + ((quad ^ sx) * 16));
            bf16x8 k11 = *reinterpret_cast<const bf16x8*>(kb + r0 + 2048 + (((quad + 4) ^ sx) * 16));
            sA0[s] = MFMA16(k00, qaA0, Z4);  sA0[s] = MFMA16(k01, qaA1, sA0[s]);
            sA1[s] = MFMA16(k10, qaA0, Z4);  sA1[s] = MFMA16(k11, qaA1, sA1[s]);
            sB0[s] = MFMA16(k00, qaB0, Z4);  sB0[s] = MFMA16(k01, qaB1, sB0[s]);
            sB1[s] = MFMA16(k10, qaB0, Z4);  sB1[s] = MFMA16(k11, qaB1, sB1[s]);
        }
        __builtin_amdgcn_s_setprio(0);
        // --- exp / pack / li-MFMA / PV per chunk ---
        #pragma unroll
        for (int s = 0; s < 2; ++s) {
            f32x4 pA0, pA1, pB0, pB1;
            #pragma unroll
            for (int r = 0; r < 4; ++r) {
                pA0[r] = EXP2F(sA0[s][r]);  pA1[r] = EXP2F(sA1[s][r]);
                pB0[r] = EXP2F(sB0[s][r]);  pB1[r] = EXP2F(sB1[s][r]);
            }
            bf16x8 fA = pk8(pA0, pA1);   // A-frag: slots quad*8..+7 of this chunk
            bf16x8 fB = pk8(pB0, pB1);

            __builtin_amdgcn_s_setprio(1);
            liAA = MFMA16(fA, vone, liAA);   // D[q][*] = sum_k P[q][k], all cols equal
            liBB = MFMA16(fB, vone, liBB);

            #pragma unroll
            for (int dc = 0; dc < 4; ++dc) {
                const unsigned char* vrow = vbb + (dc * 16 + l15) * 128;
                bf16x8 vv = *reinterpret_cast<const bf16x8*>(vrow + (((s * 4 + quad) ^ sx) * 16));
                OA[dc] = MFMA16(fA, vv, OA[dc]);   // D: row=q=quad*4+r, col=d=l15
                OB[dc] = MFMA16(fB, vv, OB[dc]);
            }
            __builtin_amdgcn_s_setprio(0);
        }
    };

    stage(0);
    __syncthreads();

    for (int p = 0; p < 16; ++p) {
        stage(1);
        compute(kbuf[0], vbuf[0]);
        __syncthreads();
        if (p < 15) stage(0);
        compute(kbuf[1], vbuf[1]);
        __syncthreads();
    }

    unsigned short* op = split ? op1 : op0;
    int b = bh >> 2, h = bh & 3;
    #pragma unroll
    for (int dc = 0; dc < 4; ++dc) {
        #pragma unroll
        for (int r = 0; r < 4; ++r) {
            int qA = qbase + quad * 4 + r;
            op[((size_t)(b * NN) + qA) * CC + h * HD + dc * 16 + l15]      = f2bf(OA[dc][r]);
            op[((size_t)(b * NN) + qA + 16) * CC + h * HD + dc * 16 + l15] = f2bf(OB[dc][r]);
        }
    }
    float* lp = lip + (size_t)split * (16 * NN) + (size_t)bh * NN + qbase;
    if (l15 == 0) {
        #pragma unroll
        for (int r = 0; r < 4; ++r) {
            lp[quad * 4 + r]      = liAA[r];
            lp[16 + quad * 4 + r] = liBB[r];
        }
    }
}

// ---------------- kernel 5: proj GEMM with FUSED split-combine (R5-verified) ----------------
// B-operand built in registers: read both k-split partials + lip, normalize, ds_write into
// the B tile. A (weights) stays global_load_lds. Counted vmcnt, one barrier pair per kk.
__global__ void __launch_bounds__(256)
k_proj(const unsigned short* __restrict__ ao, const unsigned short* __restrict__ p1,
       const float* __restrict__ lip,
       const unsigned short* __restrict__ wp, const float* __restrict__ pb,
       const float* __restrict__ x, float* __restrict__ out) {
    int bx = blockIdx.x, by = blockIdx.y;
    int t = threadIdx.x, wave = t >> 6, lane = t & 63;
    int l15 = lane & 15, quad = lane >> 4;
    int wm = wave >> 1, wn = wave & 1;

    __shared__ alignas(16) unsigned char At[2][4096];   // [64 rows][32 c]  (wp)
    __shared__ alignas(16) unsigned char Bt[2][4096];   // [64 tokens][32 c] (normalized O)

    const char* Ag = (const char*)wp + (size_t)by * 32768;
    int row0 = t >> 2, slot = t & 3;
    size_t a0 = (size_t)row0 * 512 + slot * 16;
    unsigned int dst0 = wave * 1024;

    int gtok = bx * 64 + row0;
    int b = gtok >> 12, n = gtok & 4095;
    size_t obase = ((size_t)(b * NN) + n) * CC + slot * 8;
    float inv[4];
    #pragma unroll
    for (int h = 0; h < 4; ++h) {
        size_t lb = (size_t)(b * 4 + h) * NN + n;
        inv[h] = 1.0f / (lip[lb] + lip[lb + (size_t)16 * NN]);
    }

    auto stageA = [&](int buf, int kk) {
        async_ld16(At[buf] + dst0, Ag + a0 + (size_t)kk * 64);
    };
    uint4 eu0, eu1, ou0, ou1;
    auto loadB = [&](uint4& r0, uint4& r1, int kk) {
        r0 = *reinterpret_cast<const uint4*>(ao + obase + kk * 32);
        r1 = *reinterpret_cast<const uint4*>(p1 + obase + kk * 32);
    };
    auto writeB = [&](int buf, const uint4& r0, const uint4& r1, float iv) {
        const unsigned short* q0 = reinterpret_cast<const unsigned short*>(&r0);
        const unsigned short* q1 = reinterpret_cast<const unsigned short*>(&r1);
        alignas(16) unsigned short o8[8];
        #pragma unroll
        for (int i = 0; i < 8; ++i) {
            float f0 = __uint_as_float((unsigned)q0[i] << 16);
            float f1 = __uint_as_float((unsigned)q1[i] << 16);
            o8[i] = f2bf((f0 + f1) * iv);
        }
        *reinterpret_cast<uint4*>(Bt[buf] + row0 * 64 + slot * 16) =
            *reinterpret_cast<const uint4*>(o8);
    };

    f32x4 acc[2][2];
    #pragma unroll
    for (int i = 0; i < 2; ++i)
        #pragma unroll
        for (int j = 0; j < 2; ++j) acc[i][j] = (f32x4){0.f, 0.f, 0.f, 0.f};

    loadB(eu0, eu1, 0);
    stageA(0, 0);
    loadB(ou0, ou1, 1);

    #pragma unroll
    for (int k2 = 0; k2 < 4; ++k2) {
        {   // ---- even kk ----
            const int kk = 2 * k2;
            WAITV(2);
            SCHED0;
            writeB(0, eu0, eu1, inv[kk >> 1]);
            WAITL0;
            SCHED0;
            SBAR;
            SCHED0;
            if (kk < 7) stageA(1, kk + 1);
            if (kk < 6) loadB(eu0, eu1, kk + 2);
            bf16x8 af[2], bf[2];
            #pragma unroll
            for (int f = 0; f < 2; ++f) {
                af[f] = *reinterpret_cast<const bf16x8*>(At[0] + (wm * 32 + f * 16 + l15) * 64 + quad * 16);
                bf[f] = *reinterpret_cast<const bf16x8*>(Bt[0] + (wn * 32 + f * 16 + l15) * 64 + quad * 16);
            }
            #pragma unroll
            for (int fm = 0; fm < 2; ++fm)
                #pragma unroll
                for (int fn = 0; fn < 2; ++fn)
                    acc[fm][fn] = MFMA16(af[fm], bf[fn], acc[fm][fn]);
        }
        {   // ---- odd kk ----
            const int kk = 2 * k2 + 1;
            if (kk < 7) { WAITV(2); } else { WAITV(0); }
            SCHED0;
            writeB(1, ou0, ou1, inv[kk >> 1]);
            WAITL0;
            SCHED0;
            SBAR;
            SCHED0;
            if (kk < 7) stageA(0, kk + 1);
            if (kk < 6) loadB(ou0, ou1, kk + 2);
            bf16x8 af[2], bf[2];
            #pragma unroll
            for (int f = 0; f < 2; ++f) {
                af[f] = *reinterpret_cast<const bf16x8*>(At[1] + (wm * 32 + f * 16 + l15) * 64 + quad * 16);
                bf[f] = *reinterpret_cast<const bf16x8*>(Bt[1] + (wn * 32 + f * 16 + l15) * 64 + quad * 16);
            }
            #pragma unroll
            for (int fm = 0; fm < 2; ++fm)
                #pragma unroll
                for (int fn = 0; fn < 2; ++fn)
                    acc[fm][fn] = MFMA16(af[fm], bf[fn], acc[fm][fn]);
        }
    }

    int nn0 = bx * 64;
    int bb = nn0 >> 12, nbase = nn0 & 4095;
    #pragma unroll
    for (int fm = 0; fm < 2; ++fm) {
        int o = by * 64 + wm * 32 + fm * 16 + quad * 4;
        float bias[4];
        #pragma unroll
        for (int r = 0; r < 4; ++r) bias[r] = pb[o + r];
        #pragma unroll
        for (int fn = 0; fn < 2; ++fn) {
            int nc = nbase + wn * 32 + fn * 16 + l15;
            #pragma unroll
            for (int r = 0; r < 4; ++r) {
                size_t idx = ((size_t)(bb * CC + o + r)) * NN + nc;
                out[idx] = acc[fm][fn][r] + bias[r] + x[idx];
            }
        }
    }
}

extern "C" void kernel_launch(void* const* d_in, const int* in_sizes, int n_in,
                              void* d_out, int out_size, void* d_ws, size_t ws_size,
                              hipStream_t stream) {
    const float* x     = (const float*)d_in[0];
    const float* gw    = (const float*)d_in[1];
    const float* gb    = (const float*)d_in[2];
    const float* qkvw  = (const float*)d_in[3];
    const float* qkvb  = (const float*)d_in[4];
    const float* projw = (const float*)d_in[5];
    const float* projb = (const float*)d_in[6];
    float* out = (float*)d_out;

    char* w = (char*)d_ws;
    size_t off = 0;
    unsigned short* qt = (unsigned short*)(w + off); off += (size_t)BB * NH * NN * HD * 2;  // 8 MB
    unsigned short* kt = (unsigned short*)(w + off); off += (size_t)BB * NH * NN * HD * 2;  // 8 MB
    unsigned short* vt = (unsigned short*)(w + off); off += (size_t)BB * NH * HD * NN * 2;  // 8 MB
    unsigned short* ao = (unsigned short*)(w + off); off += (size_t)BB * NN * CC * 2;       // 8 MB (split-0 partial)
    unsigned short* pt1 = (unsigned short*)(w + off); off += (size_t)BB * NN * CC * 2;      // 8 MB (split-1 partial)
    unsigned short* wqp = (unsigned short*)(w + off); off += (size_t)BB * 3 * CC * CC * 2;  // 1.5 MB (per-batch W')
    float* biasq = (float*)(w + off); off += (size_t)BB * 3 * CC * sizeof(float);           // 12 KB
    unsigned short* wpb = (unsigned short*)(w + off); off += (size_t)CC * CC * 2;           // 128 KB
    float* stats = (float*)(w + off); off += (size_t)BB * NG * 8 * 2 * sizeof(float);       // 4 KB (partials)
    float* lip   = (float*)(w + off); off += (size_t)2 * 16 * NN * sizeof(float);           // 512 KB

    k_prep<<<512, 256, 0, stream>>>(x, stats, projw, wpb);
    k_tab<<<768, 256, 0, stream>>>(qkvw, gw, gb, qkvb, stats, wqp, biasq);
    k_qkv<<<dim3(BB * NN / 128, 6), 256, 0, stream>>>(x, wqp, biasq, qt, kt, vt);
    k_attn<<<dim3(NN / 128, BB * NH, 2), 256, 0, stream>>>(qt, kt, vt, ao, pt1, lip);
    k_proj<<<dim3(BB * NN / 64, CC / 64), 256, 0, stream>>>(ao, pt1, lip, wpb, projb, x, out);
}

// Round 13
// 177.853 us; speedup vs baseline: 1.0190x; 1.0163x over previous
//
#include <hip/hip_runtime.h>
#include <hip/hip_bf16.h>

// Problem constants (B=4, C=256, H=W=64, groups=8, heads=4)
#define BB   4
#define CC   256
#define NN   4096      // H*W
#define NH   4
#define HD   64
#define NG   8
#define GSZ  32        // channels per group
#define EPSV 1e-5f
#define SCALE_L2E 0.18033688f   // 64^-0.5 * log2(e), folded into q so softmax uses raw exp2

typedef __bf16 bf16x8 __attribute__((ext_vector_type(8)));
typedef float  f32x4  __attribute__((ext_vector_type(4)));

#define MFMA16(a, b, c)  __builtin_amdgcn_mfma_f32_16x16x32_bf16((a), (b), (c), 0, 0, 0)

#if __has_builtin(__builtin_amdgcn_exp2f)
#define EXP2F __builtin_amdgcn_exp2f
#else
#define EXP2F exp2f
#endif

// phase-edge fences for the counted-vmcnt pipeline (T3/T4)
#define WAITV(n)  asm volatile("s_waitcnt vmcnt(" #n ")" ::: "memory")
#define WAITL0    asm volatile("s_waitcnt lgkmcnt(0)" ::: "memory")
#define SBAR      __builtin_amdgcn_s_barrier()
#define SCHED0    __builtin_amdgcn_sched_barrier(0)

__device__ inline unsigned short f2bf(float f) {
    unsigned int u = __float_as_uint(f);
    u += 0x7fffu + ((u >> 16) & 1u);   // RNE
    return (unsigned short)(u >> 16);
}

// pack 8 fp32 -> 8 bf16 (truncate: uniform relative bias cancels in O/li) for PV A-operand
__device__ __forceinline__ bf16x8 pk8(const f32x4& p0, const f32x4& p1) {
    alignas(16) unsigned int u[4];
    u[0] = __builtin_amdgcn_perm(__float_as_uint(p0[1]), __float_as_uint(p0[0]), 0x07060302u);
    u[1] = __builtin_amdgcn_perm(__float_as_uint(p0[3]), __float_as_uint(p0[2]), 0x07060302u);
    u[2] = __builtin_amdgcn_perm(__float_as_uint(p1[1]), __float_as_uint(p1[0]), 0x07060302u);
    u[3] = __builtin_amdgcn_perm(__float_as_uint(p1[3]), __float_as_uint(p1[2]), 0x07060302u);
    return *reinterpret_cast<bf16x8*>(u);
}

// async global->LDS, 16B per lane; LDS dest is wave-uniform base + lane*16
__device__ __forceinline__ void async_ld16(void* lds, const void* g) {
    __builtin_amdgcn_global_load_lds(
        (const __attribute__((address_space(1))) unsigned int*)g,
        (__attribute__((address_space(3))) unsigned int*)lds, 16, 0, 0);
}

// ---------------- kernel 1: gn stats partials (blocks 0..255) + proj weight cvt (256..511) ----------------
// Each (b,g,s) block writes its partial sum to a disjoint slot -> no memset, no atomics.
__global__ void k_prep(const float* __restrict__ x, float* __restrict__ stats,
                       const float* __restrict__ wp, unsigned short* __restrict__ op) {
    int blk = blockIdx.x;
    int t = threadIdx.x;
    if (blk >= 256) {   // proj weight conversion
        int i = (blk - 256) * 256 + t;
        if (i < CC * CC) op[i] = f2bf(wp[i]);
        return;
    }
    int b = blk >> 6, g = (blk >> 3) & 7, s = blk & 7;
    const float* p = x + ((size_t)(b * CC + g * GSZ)) * NN + s * 16384;
    float s0 = 0.f, s1 = 0.f;
    #pragma unroll
    for (int i = 0; i < 64; ++i) { float v = p[i * 256 + t]; s0 += v; s1 += v * v; }
    #pragma unroll
    for (int m = 1; m <= 32; m <<= 1) { s0 += __shfl_xor(s0, m); s1 += __shfl_xor(s1, m); }
    __shared__ float ls[8];
    int w = t >> 6;
    if ((t & 63) == 0) { ls[w * 2] = s0; ls[w * 2 + 1] = s1; }
    __syncthreads();
    if (t == 0) {
        float a0 = ls[0] + ls[2] + ls[4] + ls[6];
        float a1 = ls[1] + ls[3] + ls[5] + ls[7];
        stats[((b * NG + g) * 8 + s) * 2 + 0] = a0;
        stats[((b * NG + g) * 8 + s) * 2 + 1] = a1;
    }
}

// ------- kernel 2: fold GN affine into per-batch qkv weights + bias -------
// grid 768 (one block per output row o); weight row read ONCE, looped over 4 batches.
// W'[b][o][c] = W[o][c] * gw[c]*inv(b,g);  bias'[b][o] = qb[o] + sum_c W[o][c]*(gb[c]-mean*Ac)
__global__ void __launch_bounds__(256)
k_tab(const float* __restrict__ wq, const float* __restrict__ gw, const float* __restrict__ gb,
      const float* __restrict__ qb, const float* __restrict__ stats,
      unsigned short* __restrict__ wqp, float* __restrict__ biasq) {
    int o = blockIdx.x, c = threadIdx.x;
    int g = c >> 5;
    float w = wq[o * CC + c];
    float gwc = gw[c], gbc = gb[c];
    __shared__ float ls[4][4];
    #pragma unroll
    for (int b = 0; b < 4; ++b) {
        float s0 = 0.f, s1 = 0.f;
        #pragma unroll
        for (int s = 0; s < 8; ++s) {
            s0 += stats[((b * NG + g) * 8 + s) * 2 + 0];
            s1 += stats[((b * NG + g) * 8 + s) * 2 + 1];
        }
        float mean = s0 * (1.0f / 131072.0f);
        float var  = s1 * (1.0f / 131072.0f) - mean * mean;
        float inv  = rsqrtf(var + EPSV);
        float Ac = gwc * inv;
        float Bc = gbc - mean * Ac;
        wqp[((size_t)b * 768 + o) * CC + c] = f2bf(w * Ac);
        float p = w * Bc;
        #pragma unroll
        for (int m = 1; m <= 32; m <<= 1) p += __shfl_xor(p, m);
        if ((c & 63) == 0) ls[b][c >> 6] = p;
    }
    __syncthreads();
    if (c < 4) biasq[c * 768 + o] = qb[o] + ls[c][0] + ls[c][1] + ls[c][2] + ls[c][3];
}

// ---------------- kernel 3: QKV GEMM directly on x (fp32), GN pre-folded into W' ----------------
__global__ void __launch_bounds__(256)
k_qkv(const float* __restrict__ x, const unsigned short* __restrict__ wqp,
      const float* __restrict__ biasq,
      unsigned short* __restrict__ qt, unsigned short* __restrict__ kt,
      unsigned short* __restrict__ vt) {
    int bx = blockIdx.x, by = blockIdx.y;
    int t = threadIdx.x, wave = t >> 6, lane = t & 63;
    int l15 = lane & 15, quad = lane >> 4;
    int wm = wave >> 1, wn = wave & 1;

    // A: 2 x 8192 @ [0, 16384); B(fp32): 2 x 16384 @ [16384, 49152). V epilogue reuses all.
    __shared__ alignas(16) unsigned char smem[49152];

    int nn0 = bx * 128;
    int b = nn0 >> 12, nbase = nn0 & 4095;

    const char* Ag = (const char*)wqp + (size_t)b * 393216 + (size_t)by * 65536;
    int row0 = t >> 2, slot = t & 3;
    size_t a0 = (size_t)row0 * 512 + slot * 16;
    size_t a1 = a0 + 64 * 512;
    unsigned int dstA = wave * 1024;                    // + lane*16 by HW

    // B staging: per-lane source with row rotation.
    int colsrc = (((lane & 31) * 16) - 32 * wave) & 511;
    const char* xrow = (const char*)x +
        (((size_t)(b * CC) + (wave * 8 + (lane >> 5))) * NN + nbase) * 4 + colsrc;

    auto stage = [&](int buf, int kk) {
        async_ld16(smem + buf * 8192 + dstA,        Ag + a0 + (size_t)kk * 64);
        async_ld16(smem + buf * 8192 + 4096 + dstA, Ag + a1 + (size_t)kk * 64);
        const char* bs = xrow + (size_t)kk * 32 * NN * 4;
        unsigned char* bd = smem + 16384 + buf * 16384 + wave * 4096;
        async_ld16(bd,        bs);
        async_ld16(bd + 1024, bs + (size_t)2 * NN * 4);
        async_ld16(bd + 2048, bs + (size_t)4 * NN * 4);
        async_ld16(bd + 3072, bs + (size_t)6 * NN * 4);
    };

    // per-lane rotated column offsets for the 4 B-fragments (f = 0..3)
    int colr[4];
    #pragma unroll
    for (int f = 0; f < 4; ++f)
        colr[f] = (((wn * 64 + f * 16 + l15) * 4) + quad * 32) & 511;

    f32x4 acc[4][4];
    #pragma unroll
    for (int i = 0; i < 4; ++i)
        #pragma unroll
        for (int j = 0; j < 4; ++j) acc[i][j] = (f32x4){0.f, 0.f, 0.f, 0.f};

    stage(0, 0);
    stage(1, 1);

    for (int kk = 0; kk < 8; ++kk) {
        if (kk < 7) { WAITV(6); } else { WAITV(0); }
        SCHED0;
        SBAR;
        SCHED0;
        int cur = kk & 1;
        bf16x8 af[4], bf[4];
        #pragma unroll
        for (int f = 0; f < 4; ++f)
            af[f] = *reinterpret_cast<const bf16x8*>(smem + cur * 8192 + (wm * 64 + f * 16 + l15) * 64 + quad * 16);
        #pragma unroll
        for (int f = 0; f < 4; ++f) {
            const unsigned char* fb = smem + 16384 + cur * 16384 + quad * 4096 + colr[f];
            alignas(16) unsigned int u[4];
            #pragma unroll
            for (int jj = 0; jj < 4; ++jj) {
                float xl = *reinterpret_cast<const float*>(fb + (2 * jj) * 512);
                float xh = *reinterpret_cast<const float*>(fb + (2 * jj + 1) * 512);
                asm("v_cvt_pk_bf16_f32 %0, %1, %2" : "=v"(u[jj]) : "v"(xl), "v"(xh));
            }
            bf[f] = *reinterpret_cast<const bf16x8*>(u);
        }
        #pragma unroll
        for (int fm = 0; fm < 4; ++fm)
            #pragma unroll
            for (int fn = 0; fn < 4; ++fn)
                acc[fm][fn] = MFMA16(af[fm], bf[fn], acc[fm][fn]);
        WAITL0;
        SCHED0;
        SBAR;
        SCHED0;
        if (kk < 6) stage(cur, kk + 2);
    }

    int s = by >> 1;
    if (s < 2) {
        #pragma unroll
        for (int fm = 0; fm < 4; ++fm) {
            int o = by * 128 + wm * 64 + fm * 16 + quad * 4;
            int h = (o >> 6) & 3, d0 = o & 63;
            float bias[4];
            #pragma unroll
            for (int r = 0; r < 4; ++r) bias[r] = biasq[b * 768 + o + r];
            #pragma unroll
            for (int fn = 0; fn < 4; ++fn) {
                int n = nbase + wn * 64 + fn * 16 + l15;
                alignas(8) unsigned short o4[4];
                if (s == 0) {
                    #pragma unroll
                    for (int r = 0; r < 4; ++r) o4[r] = f2bf((acc[fm][fn][r] + bias[r]) * SCALE_L2E);
                    *reinterpret_cast<uint2*>(qt + (((size_t)(b * NH + h) * NN) + n) * HD + d0) =
                        *reinterpret_cast<const uint2*>(o4);
                } else {
                    #pragma unroll
                    for (int r = 0; r < 4; ++r) o4[r] = f2bf(acc[fm][fn][r] + bias[r]);
                    *reinterpret_cast<uint2*>(kt + (((size_t)(b * NH + h) * NN) + n) * HD + d0) =
                        *reinterpret_cast<const uint2*>(o4);
                }
            }
        }
    } else {
        // ---- V: repack 128(d) x 128(n) tile via LDS, coalesced uint4 stores ----
        unsigned short* vtile = (unsigned short*)smem;    // [128][132] bf16
        #pragma unroll
        for (int fm = 0; fm < 4; ++fm) {
            int o  = by * 128 + wm * 64 + fm * 16 + quad * 4;
            int ol = wm * 64 + fm * 16 + quad * 4;
            float bias[4];
            #pragma unroll
            for (int r = 0; r < 4; ++r) bias[r] = biasq[b * 768 + o + r];
            #pragma unroll
            for (int fn = 0; fn < 4; ++fn) {
                int nl = wn * 64 + fn * 16 + l15;
                #pragma unroll
                for (int r = 0; r < 4; ++r)
                    vtile[(ol + r) * 132 + nl] = f2bf(acc[fm][fn][r] + bias[r]);
            }
        }
        __syncthreads();
        // slot s -> key n inverse perm: n = (s2<<4)|(s4<<3)|(s3<<2)|(s&3)
        int hbase = (by - 4) * 2;
        #pragma unroll
        for (int pass = 0; pass < 8; ++pass) {
            int row  = pass * 16 + (t >> 4);          // 0..127 = local d-row
            int col0 = (t & 15) * 8;                  // slot base
            int nb = (col0 & ~31) | ((col0 & 16) >> 1) | ((col0 & 8) >> 1);
            const unsigned short* src = vtile + row * 132 + nb;
            uint2 lo = *reinterpret_cast<const uint2*>(src);
            uint2 hi = *reinterpret_cast<const uint2*>(src + 16);
            uint4 o4 = make_uint4(lo.x, lo.y, hi.x, hi.y);
            int h = hbase + (row >> 6), d = row & 63;
            *reinterpret_cast<uint4*>(vt + ((size_t)(b * NH + h) * HD + d) * NN + nbase + col0) = o4;
        }
    }
}

// ---------------- kernel 4: flash attention, no k-split, XCD-swizzled grid (T1) ----------------
// 1D grid 512. Dispatcher round-robins linear id across 8 XCDs (id%8); same-bh blocks share a
// 1 MB K/V panel, so the default (32,16) grid sprays each panel over all 8 private L2s
// (FETCH 69.7 MB vs ~24 ideal). Remap: xcd=lid&7, slot=lid>>3, bh=xcd+8*(slot>>5),
// qtile=slot&31 -> XCD k serves bh {k,k+8} only (2 MB working set < 4 MB L2). Bijective.
// Body = R9-verified: 64 key-tiles, li-MFMA row-sums, lane-local normalization, no partials.
__global__ void __launch_bounds__(256, 4)
k_attn(const unsigned short* __restrict__ qt, const unsigned short* __restrict__ kt,
       const unsigned short* __restrict__ vt, unsigned short* __restrict__ ao) {
    int lid = blockIdx.x;
    int xcd = lid & 7, slot = lid >> 3;
    int bh = xcd + ((slot >> 5) << 3);      // XCD k -> bh in {k, k+8}
    int qtile = slot & 31;
    int t = threadIdx.x, wave = t >> 6, lane = t & 63;
    int l15 = lane & 15, quad = lane >> 4;
    int qbase = qtile * 128 + wave * 32;
    const unsigned short* qp = qt + (size_t)bh * NN * HD;
    const unsigned short* kp = kt + (size_t)bh * NN * HD;
    const unsigned short* vp = vt + (size_t)bh * HD * NN;

    __shared__ alignas(16) unsigned char kbuf[2][8192];   // [64 keys][128 B]
    __shared__ alignas(16) unsigned char vbuf[2][8192];   // [64 d][128 B] (keys slot-permuted)

    int lr8 = lane >> 3, lc8 = lane & 7;
    int swz = lc8 ^ lr8;
    const char* ksrc = (const char*)kp + (size_t)(wave * 16 + lr8) * 128 + swz * 16;
    const char* vsrc = (const char*)vp + (size_t)(wave * 16 + lr8) * 8192 + swz * 16;
    unsigned int dstw = wave * 2048;                // + lane*16 by HW

    auto stage = [&](int buf) {                     // stages next 64-key tile, advances
        async_ld16(kbuf[buf] + dstw,        ksrc);
        async_ld16(kbuf[buf] + dstw + 1024, ksrc + 1024);       // K rows +8
        ksrc += 8192;
        async_ld16(vbuf[buf] + dstw,        vsrc);
        async_ld16(vbuf[buf] + dstw + 1024, vsrc + 8 * 8192);   // d-rows +8
        vsrc += 128;
    };

    bf16x8 qaA0 = *reinterpret_cast<const bf16x8*>(qp + (size_t)(qbase + l15) * HD + quad * 8);
    bf16x8 qaA1 = *reinterpret_cast<const bf16x8*>(qp + (size_t)(qbase + l15) * HD + 32 + quad * 8);
    bf16x8 qaB0 = *reinterpret_cast<const bf16x8*>(qp + (size_t)(qbase + 16 + l15) * HD + quad * 8);
    bf16x8 qaB1 = *reinterpret_cast<const bf16x8*>(qp + (size_t)(qbase + 16 + l15) * HD + 32 + quad * 8);

    const f32x4 Z4 = (f32x4){0.f, 0.f, 0.f, 0.f};   // persistent zero C-operand
    bf16x8 vone;
    #pragma unroll
    for (int i = 0; i < 8; ++i) vone[i] = (__bf16)1.0f;

    f32x4 OA[4], OB[4];
    #pragma unroll
    for (int i = 0; i < 4; ++i) { OA[i] = Z4; OB[i] = Z4; }
    f32x4 liAA = Z4, liBB = Z4;     // row-sum accumulators: [r] = li for query quad*4+r (+16 for B)

    int sx = l15 & 7;

    auto compute = [&](const unsigned char* kb, const unsigned char* vbb) {
        f32x4 sA0[2], sA1[2], sB0[2], sB1[2];
        // --- QK burst: both chunks, 16 independent MFMAs, C seeded from Z4 ---
        __builtin_amdgcn_s_setprio(1);
        #pragma unroll
        for (int s = 0; s < 2; ++s) {
            int r0 = (s * 32 + l15) * 128;
            bf16x8 k00 = *reinterpret_cast<const bf16x8*>(kb + r0 + ((quad ^ sx) * 16));
            bf16x8 k01 = *reinterpret_cast<const bf16x8*>(kb + r0 + (((quad + 4) ^ sx) * 16));
            bf16x8 k10 = *reinterpret_cast<const bf16x8*>(kb + r0 + 2048 + ((quad ^ sx) * 16));
            bf16x8 k11 = *reinterpret_cast<const bf16x8*>(kb + r0 + 2048 + (((quad + 4) ^ sx) * 16));
            sA0[s] = MFMA16(k00, qaA0, Z4);  sA0[s] = MFMA16(k01, qaA1, sA0[s]);
            sA1[s] = MFMA16(k10, qaA0, Z4);  sA1[s] = MFMA16(k11, qaA1, sA1[s]);
            sB0[s] = MFMA16(k00, qaB0, Z4);  sB0[s] = MFMA16(k01, qaB1, sB0[s]);
            sB1[s] = MFMA16(k10, qaB0, Z4);  sB1[s] = MFMA16(k11, qaB1, sB1[s]);
        }
        __builtin_amdgcn_s_setprio(0);
        // --- exp / pack / li-MFMA / PV per chunk ---
        #pragma unroll
        for (int s = 0; s < 2; ++s) {
            f32x4 pA0, pA1, pB0, pB1;
            #pragma unroll
            for (int r = 0; r < 4; ++r) {
                pA0[r] = EXP2F(sA0[s][r]);  pA1[r] = EXP2F(sA1[s][r]);
                pB0[r] = EXP2F(sB0[s][r]);  pB1[r] = EXP2F(sB1[s][r]);
            }
            bf16x8 fA = pk8(pA0, pA1);   // A-frag: slots quad*8..+7 of this chunk
            bf16x8 fB = pk8(pB0, pB1);

            __builtin_amdgcn_s_setprio(1);
            liAA = MFMA16(fA, vone, liAA);   // D[q][*] = sum_k P[q][k], all cols equal
            liBB = MFMA16(fB, vone, liBB);

            #pragma unroll
            for (int dc = 0; dc < 4; ++dc) {
                const unsigned char* vrow = vbb + (dc * 16 + l15) * 128;
                bf16x8 vv = *reinterpret_cast<const bf16x8*>(vrow + (((s * 4 + quad) ^ sx) * 16));
                OA[dc] = MFMA16(fA, vv, OA[dc]);   // D: row=q=quad*4+r, col=d=l15
                OB[dc] = MFMA16(fB, vv, OB[dc]);
            }
            __builtin_amdgcn_s_setprio(0);
        }
    };

    stage(0);
    __syncthreads();

    for (int p = 0; p < 32; ++p) {      // 64 key-tiles of 64 = full 4096 keys
        stage(1);
        compute(kbuf[0], vbuf[0]);
        __syncthreads();
        if (p < 31) stage(0);
        compute(kbuf[1], vbuf[1]);
        __syncthreads();
    }

    // lane-local normalization: every lane holds li for its 4 queries (A and B chunks)
    f32x4 rA, rB;
    #pragma unroll
    for (int r = 0; r < 4; ++r) { rA[r] = 1.0f / liAA[r]; rB[r] = 1.0f / liBB[r]; }

    int b = bh >> 2, h = bh & 3;
    #pragma unroll
    for (int dc = 0; dc < 4; ++dc) {
        #pragma unroll
        for (int r = 0; r < 4; ++r) {
            int qA = qbase + quad * 4 + r;
            ao[((size_t)(b * NN) + qA) * CC + h * HD + dc * 16 + l15]      = f2bf(OA[dc][r] * rA[r]);
            ao[((size_t)(b * NN) + qA + 16) * CC + h * HD + dc * 16 + l15] = f2bf(OB[dc][r] * rB[r]);
        }
    }
}

// ---------------- kernel 5: proj GEMM 64x64 tile + bias + residual, counted-vmcnt ----------------
// B = normalized ao (bf16, token-major) -> plain global_load_lds stream like A.
__global__ void __launch_bounds__(256)
k_proj(const unsigned short* __restrict__ ao, const unsigned short* __restrict__ wp,
       const float* __restrict__ pb, const float* __restrict__ x,
       float* __restrict__ out) {
    int bx = blockIdx.x, by = blockIdx.y;
    int t = threadIdx.x, wave = t >> 6, lane = t & 63;
    int l15 = lane & 15, quad = lane >> 4;
    int wm = wave >> 1, wn = wave & 1;

    __shared__ alignas(16) unsigned char At[2][4096];   // [64 rows][32 c]
    __shared__ alignas(16) unsigned char Bt[2][4096];   // [64 tokens][32 c]

    const char* Ag = (const char*)wp + (size_t)by * 32768;
    const char* Bg = (const char*)ao + (size_t)bx * 32768;
    int row0 = t >> 2, slot = t & 3;
    size_t a0 = (size_t)row0 * 512 + slot * 16;
    unsigned int dst0 = wave * 1024;

    auto stage = [&](int buf, int kk) {
        size_t ko = (size_t)kk * 64;
        async_ld16(At[buf] + dst0, Ag + a0 + ko);
        async_ld16(Bt[buf] + dst0, Bg + a0 + ko);
    };

    f32x4 acc[2][2];
    #pragma unroll
    for (int i = 0; i < 2; ++i)
        #pragma unroll
        for (int j = 0; j < 2; ++j) acc[i][j] = (f32x4){0.f, 0.f, 0.f, 0.f};

    stage(0, 0);
    stage(1, 1);

    for (int kk = 0; kk < 8; ++kk) {
        if (kk < 7) { WAITV(2); } else { WAITV(0); }
        SCHED0;
        SBAR;
        SCHED0;
        int cur = kk & 1;
        bf16x8 af[2], bf[2];
        #pragma unroll
        for (int f = 0; f < 2; ++f) {
            af[f] = *reinterpret_cast<const bf16x8*>(At[cur] + (wm * 32 + f * 16 + l15) * 64 + quad * 16);
            bf[f] = *reinterpret_cast<const bf16x8*>(Bt[cur] + (wn * 32 + f * 16 + l15) * 64 + quad * 16);
        }
        #pragma unroll
        for (int fm = 0; fm < 2; ++fm)
            #pragma unroll
            for (int fn = 0; fn < 2; ++fn)
                acc[fm][fn] = MFMA16(af[fm], bf[fn], acc[fm][fn]);
        WAITL0;
        SCHED0;
        SBAR;
        SCHED0;
        if (kk < 6) stage(cur, kk + 2);
    }

    int nn0 = bx * 64;
    int b = nn0 >> 12, nbase = nn0 & 4095;
    #pragma unroll
    for (int fm = 0; fm < 2; ++fm) {
        int o = by * 64 + wm * 32 + fm * 16 + quad * 4;
        float bias[4];
        #pragma unroll
        for (int r = 0; r < 4; ++r) bias[r] = pb[o + r];
        #pragma unroll
        for (int fn = 0; fn < 2; ++fn) {
            int n = nbase + wn * 32 + fn * 16 + l15;
            #pragma unroll
            for (int r = 0; r < 4; ++r) {
                size_t idx = ((size_t)(b * CC + o + r)) * NN + n;
                out[idx] = acc[fm][fn][r] + bias[r] + x[idx];
            }
        }
    }
}

extern "C" void kernel_launch(void* const* d_in, const int* in_sizes, int n_in,
                              void* d_out, int out_size, void* d_ws, size_t ws_size,
                              hipStream_t stream) {
    const float* x     = (const float*)d_in[0];
    const float* gw    = (const float*)d_in[1];
    const float* gb    = (const float*)d_in[2];
    const float* qkvw  = (const float*)d_in[3];
    const float* qkvb  = (const float*)d_in[4];
    const float* projw = (const float*)d_in[5];
    const float* projb = (const float*)d_in[6];
    float* out = (float*)d_out;

    char* w = (char*)d_ws;
    size_t off = 0;
    unsigned short* qt = (unsigned short*)(w + off); off += (size_t)BB * NH * NN * HD * 2;  // 8 MB
    unsigned short* kt = (unsigned short*)(w + off); off += (size_t)BB * NH * NN * HD * 2;  // 8 MB
    unsigned short* vt = (unsigned short*)(w + off); off += (size_t)BB * NH * HD * NN * 2;  // 8 MB
    unsigned short* ao = (unsigned short*)(w + off); off += (size_t)BB * NN * CC * 2;       // 8 MB (normalized O)
    unsigned short* wqp = (unsigned short*)(w + off); off += (size_t)BB * 3 * CC * CC * 2;  // 1.5 MB (per-batch W')
    float* biasq = (float*)(w + off); off += (size_t)BB * 3 * CC * sizeof(float);           // 12 KB
    unsigned short* wpb = (unsigned short*)(w + off); off += (size_t)CC * CC * 2;           // 128 KB
    float* stats = (float*)(w + off); off += (size_t)BB * NG * 8 * 2 * sizeof(float);       // 4 KB (partials)

    k_prep<<<512, 256, 0, stream>>>(x, stats, projw, wpb);
    k_tab<<<768, 256, 0, stream>>>(qkvw, gw, gb, qkvb, stats, wqp, biasq);
    k_qkv<<<dim3(BB * NN / 128, 6), 256, 0, stream>>>(x, wqp, biasq, qt, kt, vt);
    k_attn<<<512, 256, 0, stream>>>(qt, kt, vt, ao);
    k_proj<<<dim3(BB * NN / 64, CC / 64), 256, 0, stream>>>(ao, wpb, projb, x, out);
}

// Round 14
// 175.753 us; speedup vs baseline: 1.0312x; 1.0119x over previous
//
#include <hip/hip_runtime.h>
#include <hip/hip_bf16.h>

// Problem constants (B=4, C=256, H=W=64, groups=8, heads=4)
#define BB   4
#define CC   256
#define NN   4096      // H*W
#define NH   4
#define HD   64
#define NG   8
#define GSZ  32        // channels per group
#define EPSV 1e-5f
#define SCALE_L2E 0.18033688f   // 64^-0.5 * log2(e), folded into q so softmax uses raw exp2

typedef __bf16 bf16x8 __attribute__((ext_vector_type(8)));
typedef float  f32x4  __attribute__((ext_vector_type(4)));

#define MFMA16(a, b, c)  __builtin_amdgcn_mfma_f32_16x16x32_bf16((a), (b), (c), 0, 0, 0)

#if __has_builtin(__builtin_amdgcn_exp2f)
#define EXP2F __builtin_amdgcn_exp2f
#else
#define EXP2F exp2f
#endif

// phase-edge fences for the counted-vmcnt pipeline (T3/T4)
#define WAITV(n)  asm volatile("s_waitcnt vmcnt(" #n ")" ::: "memory")
#define WAITL0    asm volatile("s_waitcnt lgkmcnt(0)" ::: "memory")
#define SBAR      __builtin_amdgcn_s_barrier()
#define SCHED0    __builtin_amdgcn_sched_barrier(0)

__device__ inline unsigned short f2bf(float f) {
    unsigned int u = __float_as_uint(f);
    u += 0x7fffu + ((u >> 16) & 1u);   // RNE
    return (unsigned short)(u >> 16);
}

// pack 8 fp32 -> 8 bf16 (truncate: uniform relative bias cancels in O/li) for PV A-operand
__device__ __forceinline__ bf16x8 pk8(const f32x4& p0, const f32x4& p1) {
    alignas(16) unsigned int u[4];
    u[0] = __builtin_amdgcn_perm(__float_as_uint(p0[1]), __float_as_uint(p0[0]), 0x07060302u);
    u[1] = __builtin_amdgcn_perm(__float_as_uint(p0[3]), __float_as_uint(p0[2]), 0x07060302u);
    u[2] = __builtin_amdgcn_perm(__float_as_uint(p1[1]), __float_as_uint(p1[0]), 0x07060302u);
    u[3] = __builtin_amdgcn_perm(__float_as_uint(p1[3]), __float_as_uint(p1[2]), 0x07060302u);
    return *reinterpret_cast<bf16x8*>(u);
}

// async global->LDS, 16B per lane; LDS dest is wave-uniform base + lane*16
__device__ __forceinline__ void async_ld16(void* lds, const void* g) {
    __builtin_amdgcn_global_load_lds(
        (const __attribute__((address_space(1))) unsigned int*)g,
        (__attribute__((address_space(3))) unsigned int*)lds, 16, 0, 0);
}

// ---------------- kernel 1: gn stats partials (blocks 0..255) + proj weight cvt (256..511) ----------------
// Each (b,g,s) block writes its partial sum to a disjoint slot -> no memset, no atomics.
__global__ void k_prep(const float* __restrict__ x, float* __restrict__ stats,
                       const float* __restrict__ wp, unsigned short* __restrict__ op) {
    int blk = blockIdx.x;
    int t = threadIdx.x;
    if (blk >= 256) {   // proj weight conversion
        int i = (blk - 256) * 256 + t;
        if (i < CC * CC) op[i] = f2bf(wp[i]);
        return;
    }
    int b = blk >> 6, g = (blk >> 3) & 7, s = blk & 7;
    const float* p = x + ((size_t)(b * CC + g * GSZ)) * NN + s * 16384;
    float s0 = 0.f, s1 = 0.f;
    #pragma unroll
    for (int i = 0; i < 64; ++i) { float v = p[i * 256 + t]; s0 += v; s1 += v * v; }
    #pragma unroll
    for (int m = 1; m <= 32; m <<= 1) { s0 += __shfl_xor(s0, m); s1 += __shfl_xor(s1, m); }
    __shared__ float ls[8];
    int w = t >> 6;
    if ((t & 63) == 0) { ls[w * 2] = s0; ls[w * 2 + 1] = s1; }
    __syncthreads();
    if (t == 0) {
        float a0 = ls[0] + ls[2] + ls[4] + ls[6];
        float a1 = ls[1] + ls[3] + ls[5] + ls[7];
        stats[((b * NG + g) * 8 + s) * 2 + 0] = a0;
        stats[((b * NG + g) * 8 + s) * 2 + 1] = a1;
    }
}

// ------- kernel 2: fold GN affine into per-batch qkv weights + bias -------
// grid 768 (one block per output row o); weight row read ONCE, looped over 4 batches.
// W'[b][o][c] = W[o][c] * gw[c]*inv(b,g);  bias'[b][o] = qb[o] + sum_c W[o][c]*(gb[c]-mean*Ac)
__global__ void __launch_bounds__(256)
k_tab(const float* __restrict__ wq, const float* __restrict__ gw, const float* __restrict__ gb,
      const float* __restrict__ qb, const float* __restrict__ stats,
      unsigned short* __restrict__ wqp, float* __restrict__ biasq) {
    int o = blockIdx.x, c = threadIdx.x;
    int g = c >> 5;
    float w = wq[o * CC + c];
    float gwc = gw[c], gbc = gb[c];
    __shared__ float ls[4][4];
    #pragma unroll
    for (int b = 0; b < 4; ++b) {
        float s0 = 0.f, s1 = 0.f;
        #pragma unroll
        for (int s = 0; s < 8; ++s) {
            s0 += stats[((b * NG + g) * 8 + s) * 2 + 0];
            s1 += stats[((b * NG + g) * 8 + s) * 2 + 1];
        }
        float mean = s0 * (1.0f / 131072.0f);
        float var  = s1 * (1.0f / 131072.0f) - mean * mean;
        float inv  = rsqrtf(var + EPSV);
        float Ac = gwc * inv;
        float Bc = gbc - mean * Ac;
        wqp[((size_t)b * 768 + o) * CC + c] = f2bf(w * Ac);
        float p = w * Bc;
        #pragma unroll
        for (int m = 1; m <= 32; m <<= 1) p += __shfl_xor(p, m);
        if ((c & 63) == 0) ls[b][c >> 6] = p;
    }
    __syncthreads();
    if (c < 4) biasq[c * 768 + o] = qb[o] + ls[c][0] + ls[c][1] + ls[c][2] + ls[c][3];
}

// ---------------- kernel 3: QKV GEMM directly on x (fp32), GN pre-folded into W' ----------------
__global__ void __launch_bounds__(256)
k_qkv(const float* __restrict__ x, const unsigned short* __restrict__ wqp,
      const float* __restrict__ biasq,
      unsigned short* __restrict__ qt, unsigned short* __restrict__ kt,
      unsigned short* __restrict__ vt) {
    int bx = blockIdx.x, by = blockIdx.y;
    int t = threadIdx.x, wave = t >> 6, lane = t & 63;
    int l15 = lane & 15, quad = lane >> 4;
    int wm = wave >> 1, wn = wave & 1;

    // A: 2 x 8192 @ [0, 16384); B(fp32): 2 x 16384 @ [16384, 49152). V epilogue reuses all.
    __shared__ alignas(16) unsigned char smem[49152];

    int nn0 = bx * 128;
    int b = nn0 >> 12, nbase = nn0 & 4095;

    const char* Ag = (const char*)wqp + (size_t)b * 393216 + (size_t)by * 65536;
    int row0 = t >> 2, slot = t & 3;
    size_t a0 = (size_t)row0 * 512 + slot * 16;
    size_t a1 = a0 + 64 * 512;
    unsigned int dstA = wave * 1024;                    // + lane*16 by HW

    // B staging: per-lane source with row rotation.
    int colsrc = (((lane & 31) * 16) - 32 * wave) & 511;
    const char* xrow = (const char*)x +
        (((size_t)(b * CC) + (wave * 8 + (lane >> 5))) * NN + nbase) * 4 + colsrc;

    auto stage = [&](int buf, int kk) {
        async_ld16(smem + buf * 8192 + dstA,        Ag + a0 + (size_t)kk * 64);
        async_ld16(smem + buf * 8192 + 4096 + dstA, Ag + a1 + (size_t)kk * 64);
        const char* bs = xrow + (size_t)kk * 32 * NN * 4;
        unsigned char* bd = smem + 16384 + buf * 16384 + wave * 4096;
        async_ld16(bd,        bs);
        async_ld16(bd + 1024, bs + (size_t)2 * NN * 4);
        async_ld16(bd + 2048, bs + (size_t)4 * NN * 4);
        async_ld16(bd + 3072, bs + (size_t)6 * NN * 4);
    };

    // per-lane rotated column offsets for the 4 B-fragments (f = 0..3)
    int colr[4];
    #pragma unroll
    for (int f = 0; f < 4; ++f)
        colr[f] = (((wn * 64 + f * 16 + l15) * 4) + quad * 32) & 511;

    f32x4 acc[4][4];
    #pragma unroll
    for (int i = 0; i < 4; ++i)
        #pragma unroll
        for (int j = 0; j < 4; ++j) acc[i][j] = (f32x4){0.f, 0.f, 0.f, 0.f};

    stage(0, 0);
    stage(1, 1);

    for (int kk = 0; kk < 8; ++kk) {
        if (kk < 7) { WAITV(6); } else { WAITV(0); }
        SCHED0;
        SBAR;
        SCHED0;
        int cur = kk & 1;
        bf16x8 af[4], bf[4];
        #pragma unroll
        for (int f = 0; f < 4; ++f)
            af[f] = *reinterpret_cast<const bf16x8*>(smem + cur * 8192 + (wm * 64 + f * 16 + l15) * 64 + quad * 16);
        #pragma unroll
        for (int f = 0; f < 4; ++f) {
            const unsigned char* fb = smem + 16384 + cur * 16384 + quad * 4096 + colr[f];
            alignas(16) unsigned int u[4];
            #pragma unroll
            for (int jj = 0; jj < 4; ++jj) {
                float xl = *reinterpret_cast<const float*>(fb + (2 * jj) * 512);
                float xh = *reinterpret_cast<const float*>(fb + (2 * jj + 1) * 512);
                asm("v_cvt_pk_bf16_f32 %0, %1, %2" : "=v"(u[jj]) : "v"(xl), "v"(xh));
            }
            bf[f] = *reinterpret_cast<const bf16x8*>(u);
        }
        #pragma unroll
        for (int fm = 0; fm < 4; ++fm)
            #pragma unroll
            for (int fn = 0; fn < 4; ++fn)
                acc[fm][fn] = MFMA16(af[fm], bf[fn], acc[fm][fn]);
        WAITL0;
        SCHED0;
        SBAR;
        SCHED0;
        if (kk < 6) stage(cur, kk + 2);
    }

    int s = by >> 1;
    if (s < 2) {
        #pragma unroll
        for (int fm = 0; fm < 4; ++fm) {
            int o = by * 128 + wm * 64 + fm * 16 + quad * 4;
            int h = (o >> 6) & 3, d0 = o & 63;
            float bias[4];
            #pragma unroll
            for (int r = 0; r < 4; ++r) bias[r] = biasq[b * 768 + o + r];
            #pragma unroll
            for (int fn = 0; fn < 4; ++fn) {
                int n = nbase + wn * 64 + fn * 16 + l15;
                alignas(8) unsigned short o4[4];
                if (s == 0) {
                    #pragma unroll
                    for (int r = 0; r < 4; ++r) o4[r] = f2bf((acc[fm][fn][r] + bias[r]) * SCALE_L2E);
                    *reinterpret_cast<uint2*>(qt + (((size_t)(b * NH + h) * NN) + n) * HD + d0) =
                        *reinterpret_cast<const uint2*>(o4);
                } else {
                    #pragma unroll
                    for (int r = 0; r < 4; ++r) o4[r] = f2bf(acc[fm][fn][r] + bias[r]);
                    *reinterpret_cast<uint2*>(kt + (((size_t)(b * NH + h) * NN) + n) * HD + d0) =
                        *reinterpret_cast<const uint2*>(o4);
                }
            }
        }
    } else {
        // ---- V: repack 128(d) x 128(n) tile via LDS, coalesced uint4 stores ----
        unsigned short* vtile = (unsigned short*)smem;    // [128][132] bf16
        #pragma unroll
        for (int fm = 0; fm < 4; ++fm) {
            int o  = by * 128 + wm * 64 + fm * 16 + quad * 4;
            int ol = wm * 64 + fm * 16 + quad * 4;
            float bias[4];
            #pragma unroll
            for (int r = 0; r < 4; ++r) bias[r] = biasq[b * 768 + o + r];
            #pragma unroll
            for (int fn = 0; fn < 4; ++fn) {
                int nl = wn * 64 + fn * 16 + l15;
                #pragma unroll
                for (int r = 0; r < 4; ++r)
                    vtile[(ol + r) * 132 + nl] = f2bf(acc[fm][fn][r] + bias[r]);
            }
        }
        __syncthreads();
        // slot s -> key n inverse perm: n = (s2<<4)|(s4<<3)|(s3<<2)|(s&3)
        int hbase = (by - 4) * 2;
        #pragma unroll
        for (int pass = 0; pass < 8; ++pass) {
            int row  = pass * 16 + (t >> 4);          // 0..127 = local d-row
            int col0 = (t & 15) * 8;                  // slot base
            int nb = (col0 & ~31) | ((col0 & 16) >> 1) | ((col0 & 8) >> 1);
            const unsigned short* src = vtile + row * 132 + nb;
            uint2 lo = *reinterpret_cast<const uint2*>(src);
            uint2 hi = *reinterpret_cast<const uint2*>(src + 16);
            uint4 o4 = make_uint4(lo.x, lo.y, hi.x, hi.y);
            int h = hbase + (row >> 6), d = row & 63;
            *reinterpret_cast<uint4*>(vt + ((size_t)(b * NH + h) * HD + d) * NN + nbase + col0) = o4;
        }
    }
}

// ---------------- kernel 4: flash attention, in-block k-split (8 waves), XCD swizzle ----------------
// 1D grid 512, block 512 = 8 waves. Wave group g = wave>>2 handles keys g*2048..g*2048+2047
// for the SAME 128 queries (wave-in-group wg owns queries wg*32..). Restores 16 waves/CU
// (2 blocks x 8; LDS 64 KB -> exactly 2 blocks/CU) matching split-2's residency, while the
// split-combine is an intra-block LDS exchange (group 1 -> group 0, stride-41 pad, one extra
// barrier) instead of 25 MB of partial/lip HBM round-trip. XCD swizzle (R13: FETCH 69.7->12.3
// MB) retained: xcd=lid&7 serves bh {xcd, xcd+8} only. li-MFMA row-sums stay lane-local ->
// group-0 normalization needs no shuffles; ao written normalized bf16 (k_proj plain stream).
__global__ void __launch_bounds__(512, 4)
k_attn(const unsigned short* __restrict__ qt, const unsigned short* __restrict__ kt,
       const unsigned short* __restrict__ vt, unsigned short* __restrict__ ao) {
    int lid = blockIdx.x;
    int xcd = lid & 7, slot = lid >> 3;
    int bh = xcd + ((slot >> 5) << 3);      // XCD k -> bh in {k, k+8}
    int qtile = slot & 31;
    int t = threadIdx.x, wave = t >> 6, lane = t & 63;
    int grp = wave >> 2, wg = wave & 3;
    int l15 = lane & 15, quad = lane >> 4;
    int qbase = qtile * 128 + wg * 32;
    int kbase = grp * 2048;
    const unsigned short* qp = qt + (size_t)bh * NN * HD;
    const unsigned short* kp = kt + (size_t)bh * NN * HD;
    const unsigned short* vp = vt + (size_t)bh * HD * NN;

    // [0,32768): K bufs [grp][buf][8192]; [32768,65536): V bufs. Epilogue exchange reuses.
    __shared__ alignas(16) unsigned char smem[65536];

    int lr8 = lane >> 3, lc8 = lane & 7;
    int swz = lc8 ^ lr8;
    const char* ksrc = (const char*)kp + (size_t)(kbase + wg * 16 + lr8) * 128 + swz * 16;
    const char* vsrc = (const char*)vp + (size_t)(wg * 16 + lr8) * 8192 + (size_t)kbase * 2 + swz * 16;
    unsigned int dstw = wg * 2048;                  // + lane*16 by HW

    auto stage = [&](int buf) {                     // stages next 64-key tile, advances
        unsigned char* kb = smem + grp * 16384 + buf * 8192;
        unsigned char* vb = smem + 32768 + grp * 16384 + buf * 8192;
        async_ld16(kb + dstw,        ksrc);
        async_ld16(kb + dstw + 1024, ksrc + 1024);              // K rows +8
        ksrc += 8192;
        async_ld16(vb + dstw,        vsrc);
        async_ld16(vb + dstw + 1024, vsrc + 8 * 8192);          // d-rows +8
        vsrc += 128;
    };

    bf16x8 qaA0 = *reinterpret_cast<const bf16x8*>(qp + (size_t)(qbase + l15) * HD + quad * 8);
    bf16x8 qaA1 = *reinterpret_cast<const bf16x8*>(qp + (size_t)(qbase + l15) * HD + 32 + quad * 8);
    bf16x8 qaB0 = *reinterpret_cast<const bf16x8*>(qp + (size_t)(qbase + 16 + l15) * HD + quad * 8);
    bf16x8 qaB1 = *reinterpret_cast<const bf16x8*>(qp + (size_t)(qbase + 16 + l15) * HD + 32 + quad * 8);

    const f32x4 Z4 = (f32x4){0.f, 0.f, 0.f, 0.f};   // persistent zero C-operand
    bf16x8 vone;
    #pragma unroll
    for (int i = 0; i < 8; ++i) vone[i] = (__bf16)1.0f;

    f32x4 OA[4], OB[4];
    #pragma unroll
    for (int i = 0; i < 4; ++i) { OA[i] = Z4; OB[i] = Z4; }
    f32x4 liAA = Z4, liBB = Z4;     // row-sum accumulators: [r] = li for query quad*4+r (+16 for B)

    int sx = l15 & 7;

    auto compute = [&](int buf) {
        const unsigned char* kb = smem + grp * 16384 + buf * 8192;
        const unsigned char* vbb = smem + 32768 + grp * 16384 + buf * 8192;
        f32x4 sA0[2], sA1[2], sB0[2], sB1[2];
        // --- QK burst: both chunks, 16 independent MFMAs, C seeded from Z4 ---
        __builtin_amdgcn_s_setprio(1);
        #pragma unroll
        for (int s = 0; s < 2; ++s) {
            int r0 = (s * 32 + l15) * 128;
            bf16x8 k00 = *reinterpret_cast<const bf16x8*>(kb + r0 + ((quad ^ sx) * 16));
            bf16x8 k01 = *reinterpret_cast<const bf16x8*>(kb + r0 + (((quad + 4) ^ sx) * 16));
            bf16x8 k10 = *reinterpret_cast<const bf16x8*>(kb + r0 + 2048 + ((quad ^ sx) * 16));
            bf16x8 k11 = *reinterpret_cast<const bf16x8*>(kb + r0 + 2048 + (((quad + 4) ^ sx) * 16));
            sA0[s] = MFMA16(k00, qaA0, Z4);  sA0[s] = MFMA16(k01, qaA1, sA0[s]);
            sA1[s] = MFMA16(k10, qaA0, Z4);  sA1[s] = MFMA16(k11, qaA1, sA1[s]);
            sB0[s] = MFMA16(k00, qaB0, Z4);  sB0[s] = MFMA16(k01, qaB1, sB0[s]);
            sB1[s] = MFMA16(k10, qaB0, Z4);  sB1[s] = MFMA16(k11, qaB1, sB1[s]);
        }
        __builtin_amdgcn_s_setprio(0);
        // --- exp / pack / li-MFMA / PV per chunk ---
        #pragma unroll
        for (int s = 0; s < 2; ++s) {
            f32x4 pA0, pA1, pB0, pB1;
            #pragma unroll
            for (int r = 0; r < 4; ++r) {
                pA0[r] = EXP2F(sA0[s][r]);  pA1[r] = EXP2F(sA1[s][r]);
                pB0[r] = EXP2F(sB0[s][r]);  pB1[r] = EXP2F(sB1[s][r]);
            }
            bf16x8 fA = pk8(pA0, pA1);   // A-frag: slots quad*8..+7 of this chunk
            bf16x8 fB = pk8(pB0, pB1);

            __builtin_amdgcn_s_setprio(1);
            liAA = MFMA16(fA, vone, liAA);   // D[q][*] = sum_k P[q][k], all cols equal
            liBB = MFMA16(fB, vone, liBB);

            #pragma unroll
            for (int dc = 0; dc < 4; ++dc) {
                const unsigned char* vrow = vbb + (dc * 16 + l15) * 128;
                bf16x8 vv = *reinterpret_cast<const bf16x8*>(vrow + (((s * 4 + quad) ^ sx) * 16));
                OA[dc] = MFMA16(fA, vv, OA[dc]);   // D: row=q=quad*4+r, col=d=l15
                OB[dc] = MFMA16(fB, vv, OB[dc]);
            }
            __builtin_amdgcn_s_setprio(0);
        }
    };

    stage(0);
    __syncthreads();

    for (int p = 0; p < 16; ++p) {      // 32 tiles per group = group's 2048 keys
        stage(1);
        compute(0);
        __syncthreads();
        if (p < 15) stage(0);
        compute(1);
        __syncthreads();
    }

    // ---- intra-block split combine: group 1 -> LDS (stride 41 floats, conflict-free),
    //      group 0 adds, normalizes lane-locally, stores ----
    float* xch = (float*)smem;
    int xi = (wg * 64 + lane) * 41;
    if (grp == 1) {
        #pragma unroll
        for (int dc = 0; dc < 4; ++dc)
            #pragma unroll
            for (int r = 0; r < 4; ++r) {
                xch[xi + dc * 4 + r]      = OA[dc][r];
                xch[xi + 16 + dc * 4 + r] = OB[dc][r];
            }
        #pragma unroll
        for (int r = 0; r < 4; ++r) { xch[xi + 32 + r] = liAA[r]; xch[xi + 36 + r] = liBB[r]; }
    }
    __syncthreads();
    if (grp == 0) {
        #pragma unroll
        for (int dc = 0; dc < 4; ++dc)
            #pragma unroll
            for (int r = 0; r < 4; ++r) {
                OA[dc][r] += xch[xi + dc * 4 + r];
                OB[dc][r] += xch[xi + 16 + dc * 4 + r];
            }
        #pragma unroll
        for (int r = 0; r < 4; ++r) { liAA[r] += xch[xi + 32 + r]; liBB[r] += xch[xi + 36 + r]; }

        f32x4 rA, rB;
        #pragma unroll
        for (int r = 0; r < 4; ++r) { rA[r] = 1.0f / liAA[r]; rB[r] = 1.0f / liBB[r]; }

        int b = bh >> 2, h = bh & 3;
        #pragma unroll
        for (int dc = 0; dc < 4; ++dc) {
            #pragma unroll
            for (int r = 0; r < 4; ++r) {
                int qA = qbase + quad * 4 + r;
                ao[((size_t)(b * NN) + qA) * CC + h * HD + dc * 16 + l15]      = f2bf(OA[dc][r] * rA[r]);
                ao[((size_t)(b * NN) + qA + 16) * CC + h * HD + dc * 16 + l15] = f2bf(OB[dc][r] * rB[r]);
            }
        }
    }
}

// ---------------- kernel 5: proj GEMM 64x64 tile + bias + residual, counted-vmcnt ----------------
// B = normalized ao (bf16, token-major) -> plain global_load_lds stream like A.
__global__ void __launch_bounds__(256)
k_proj(const unsigned short* __restrict__ ao, const unsigned short* __restrict__ wp,
       const float* __restrict__ pb, const float* __restrict__ x,
       float* __restrict__ out) {
    int bx = blockIdx.x, by = blockIdx.y;
    int t = threadIdx.x, wave = t >> 6, lane = t & 63;
    int l15 = lane & 15, quad = lane >> 4;
    int wm = wave >> 1, wn = wave & 1;

    __shared__ alignas(16) unsigned char At[2][4096];   // [64 rows][32 c]
    __shared__ alignas(16) unsigned char Bt[2][4096];   // [64 tokens][32 c]

    const char* Ag = (const char*)wp + (size_t)by * 32768;
    const char* Bg = (const char*)ao + (size_t)bx * 32768;
    int row0 = t >> 2, slot = t & 3;
    size_t a0 = (size_t)row0 * 512 + slot * 16;
    unsigned int dst0 = wave * 1024;

    auto stage = [&](int buf, int kk) {
        size_t ko = (size_t)kk * 64;
        async_ld16(At[buf] + dst0, Ag + a0 + ko);
        async_ld16(Bt[buf] + dst0, Bg + a0 + ko);
    };

    f32x4 acc[2][2];
    #pragma unroll
    for (int i = 0; i < 2; ++i)
        #pragma unroll
        for (int j = 0; j < 2; ++j) acc[i][j] = (f32x4){0.f, 0.f, 0.f, 0.f};

    stage(0, 0);
    stage(1, 1);

    for (int kk = 0; kk < 8; ++kk) {
        if (kk < 7) { WAITV(2); } else { WAITV(0); }
        SCHED0;
        SBAR;
        SCHED0;
        int cur = kk & 1;
        bf16x8 af[2], bf[2];
        #pragma unroll
        for (int f = 0; f < 2; ++f) {
            af[f] = *reinterpret_cast<const bf16x8*>(At[cur] + (wm * 32 + f * 16 + l15) * 64 + quad * 16);
            bf[f] = *reinterpret_cast<const bf16x8*>(Bt[cur] + (wn * 32 + f * 16 + l15) * 64 + quad * 16);
        }
        #pragma unroll
        for (int fm = 0; fm < 2; ++fm)
            #pragma unroll
            for (int fn = 0; fn < 2; ++fn)
                acc[fm][fn] = MFMA16(af[fm], bf[fn], acc[fm][fn]);
        WAITL0;
        SCHED0;
        SBAR;
        SCHED0;
        if (kk < 6) stage(cur, kk + 2);
    }

    int nn0 = bx * 64;
    int b = nn0 >> 12, nbase = nn0 & 4095;
    #pragma unroll
    for (int fm = 0; fm < 2; ++fm) {
        int o = by * 64 + wm * 32 + fm * 16 + quad * 4;
        float bias[4];
        #pragma unroll
        for (int r = 0; r < 4; ++r) bias[r] = pb[o + r];
        #pragma unroll
        for (int fn = 0; fn < 2; ++fn) {
            int n = nbase + wn * 32 + fn * 16 + l15;
            #pragma unroll
            for (int r = 0; r < 4; ++r) {
                size_t idx = ((size_t)(b * CC + o + r)) * NN + n;
                out[idx] = acc[fm][fn][r] + bias[r] + x[idx];
            }
        }
    }
}

extern "C" void kernel_launch(void* const* d_in, const int* in_sizes, int n_in,
                              void* d_out, int out_size, void* d_ws, size_t ws_size,
                              hipStream_t stream) {
    const float* x     = (const float*)d_in[0];
    const float* gw    = (const float*)d_in[1];
    const float* gb    = (const float*)d_in[2];
    const float* qkvw  = (const float*)d_in[3];
    const float* qkvb  = (const float*)d_in[4];
    const float* projw = (const float*)d_in[5];
    const float* projb = (const float*)d_in[6];
    float* out = (float*)d_out;

    char* w = (char*)d_ws;
    size_t off = 0;
    unsigned short* qt = (unsigned short*)(w + off); off += (size_t)BB * NH * NN * HD * 2;  // 8 MB
    unsigned short* kt = (unsigned short*)(w + off); off += (size_t)BB * NH * NN * HD * 2;  // 8 MB
    unsigned short* vt = (unsigned short*)(w + off); off += (size_t)BB * NH * HD * NN * 2;  // 8 MB
    unsigned short* ao = (unsigned short*)(w + off); off += (size_t)BB * NN * CC * 2;       // 8 MB (normalized O)
    unsigned short* wqp = (unsigned short*)(w + off); off += (size_t)BB * 3 * CC * CC * 2;  // 1.5 MB (per-batch W')
    float* biasq = (float*)(w + off); off += (size_t)BB * 3 * CC * sizeof(float);           // 12 KB
    unsigned short* wpb = (unsigned short*)(w + off); off += (size_t)CC * CC * 2;           // 128 KB
    float* stats = (float*)(w + off); off += (size_t)BB * NG * 8 * 2 * sizeof(float);       // 4 KB (partials)

    k_prep<<<512, 256, 0, stream>>>(x, stats, projw, wpb);
    k_tab<<<768, 256, 0, stream>>>(qkvw, gw, gb, qkvb, stats, wqp, biasq);
    k_qkv<<<dim3(BB * NN / 128, 6), 256, 0, stream>>>(x, wqp, biasq, qt, kt, vt);
    k_attn<<<512, 512, 0, stream>>>(qt, kt, vt, ao);
    k_proj<<<dim3(BB * NN / 64, CC / 64), 256, 0, stream>>>(ao, wpb, projb, x, out);
}